// Round 1
// baseline (12824.142 us; speedup 1.0000x reference)
//
#include <hip/hip_runtime.h>
#include <math.h>

// ---------------- problem dims ----------------
#define BB 8
#define RR 12
#define WIDTH 2304
#define TT 4
#define HH 16
#define WW 29
#define HWIN (HH*WW)        // 464
#define REDUCE 1024
#define HID 512
#define NC 60
#define DEPTH 2
#define NIMG (BB*RR)        // 96
#define OH2 14              // conv2 output (valid 3x3 on 16x29)
#define OW2 27
#define NSP2 (OH2*OW2)      // 378
#define PH 7                // pooled spatial
#define PW 14
#define NSP (PH*PW)         // 98
#define ATT_SCALE 0.044194173824159216f   // 1/sqrt(512)

// ---------------- unified tiled GEMM / implicit-GEMM conv ----------------
// MODE 0: plain GEMM, B = dense (K x N) per batch z (stride bstride)
// MODE 1: conv2 loader: B built on the fly = relu(bgpart[b] + bias1[z]), valid 3x3, in 16x29 -> 14x27
// MODE 2: pad-1 3x3 conv loader on 7x14 (hr2o convs)
// MODE 3: like MODE 2 but blockIdx.y selects one of 3 weight/output sets (fused q,k,v)
#define TS 128
#define KC 8

template<int MODE, bool RELU, bool RESID>
__global__ __launch_bounds__(256)
void gemm_k(const float* __restrict__ A0, const float* __restrict__ A1, const float* __restrict__ A2,
            int lda,
            const float* __restrict__ Bm, long bstride,
            const float* __restrict__ bias,
            const float* __restrict__ Res,
            float* __restrict__ Y0, float* __restrict__ Y1, float* __restrict__ Y2,
            int M, int N, int K)
{
    constexpr int LOADER = (MODE == 3) ? 2 : MODE;
    __shared__ float As[KC][TS + 4];
    __shared__ float Bs[KC][TS + 4];
    const int tid = threadIdx.x;
    const int tx = tid & 15, ty = tid >> 4;
    const int n0 = blockIdx.x * TS;
    int by = blockIdx.y;
    const int z = blockIdx.z;

    const float* A = A0;
    float* Y = Y0;
    if (MODE == 3) {
        int sel = by >> 2; by &= 3;
        if (sel == 1) { A = A1; Y = Y1; }
        else if (sel == 2) { A = A2; Y = Y2; }
    }
    const int m0 = by * TS;

    // loader thread maps
    const int a_k  = tid & (KC - 1);   // 0..7
    const int a_m0 = tid >> 3;         // 0..31
    const int b_n  = tid & (TS - 1);   // 0..127
    const int b_k0 = tid >> 7;         // 0..1

    // hoisted per-thread spatial indices for conv loaders (b_n fixed)
    int oh = 0, ow = 0, bimg = 0;
    if (LOADER == 1) { int n = n0 + b_n; oh = n / OW2; ow = n % OW2; bimg = z / RR; }
    if (LOADER == 2) { int n = n0 + b_n; oh = n / PW;  ow = n % PW; }

    float acc[8][8];
#pragma unroll
    for (int i = 0; i < 8; ++i)
#pragma unroll
        for (int j = 0; j < 8; ++j) acc[i][j] = 0.f;

    for (int k0 = 0; k0 < K; k0 += KC) {
        // stage A tile (TS x KC) -> As[k][m]
#pragma unroll
        for (int r = 0; r < 4; ++r) {
            int m = a_m0 + r * 32;
            As[a_k][m] = A[(long)(m0 + m) * lda + (k0 + a_k)];
        }
        // stage B tile (KC x TS) -> Bs[k][n]
#pragma unroll
        for (int r = 0; r < 4; ++r) {
            int kk = b_k0 * 4 + r;
            int kg = k0 + kk;
            int n = n0 + b_n;
            float v = 0.f;
            if (LOADER == 0) {
                if (n < N) v = Bm[(long)z * bstride + (long)kg * N + n];
            } else if (LOADER == 1) {
                if (n < N) {
                    int ci = kg / 9; int tap = kg - ci * 9;
                    int kh = tap / 3, kw = tap - kh * 3;
                    float t = Bm[((long)(bimg * HID + ci)) * HWIN + (oh + kh) * WW + (ow + kw)]
                            + bias[z * HID + ci];
                    v = fmaxf(t, 0.f);
                }
            } else { // LOADER 2: pad-1 conv on 7x14
                if (n < N) {
                    int ci = kg / 9; int tap = kg - ci * 9;
                    int kh = tap / 3, kw = tap - kh * 3;
                    int ih = oh + kh - 1, iw = ow + kw - 1;
                    if ((unsigned)ih < (unsigned)PH && (unsigned)iw < (unsigned)PW)
                        v = Bm[((long)(z * HID + ci)) * NSP + ih * PW + iw];
                }
            }
            Bs[kk][b_n] = v;
        }
        __syncthreads();
#pragma unroll
        for (int kk = 0; kk < KC; ++kk) {
            float a[8], b[8];
#pragma unroll
            for (int i = 0; i < 8; ++i) a[i] = As[kk][ty * 8 + i];
#pragma unroll
            for (int j = 0; j < 8; ++j) b[j] = Bs[kk][tx * 8 + j];
#pragma unroll
            for (int i = 0; i < 8; ++i)
#pragma unroll
                for (int j = 0; j < 8; ++j) acc[i][j] = fmaf(a[i], b[j], acc[i][j]);
        }
        __syncthreads();
    }
    // epilogue
#pragma unroll
    for (int i = 0; i < 8; ++i) {
        int m = m0 + ty * 8 + i;
#pragma unroll
        for (int j = 0; j < 8; ++j) {
            int n = n0 + tx * 8 + j;
            if (n < N) {
                float v = acc[i][j];
                if (RESID) v += Res[((long)z * M + m) * N + n];
                if (RELU) v = fmaxf(v, 0.f);
                Y[((long)z * M + m) * N + n] = v;
            }
        }
    }
}

// ---------------- temporal mean ----------------
__global__ void tmean_k(const float* __restrict__ f, float* __restrict__ o, int total)
{
    int i = blockIdx.x * blockDim.x + threadIdx.x;
    if (i >= total) return;
    int p = i % HWIN; long bc = i / HWIN;
    const float* src = f + bc * (long)TT * HWIN + p;
    o[i] = (src[0] + src[HWIN] + src[2 * HWIN] + src[3 * HWIN]) * 0.25f;
}

// ---------------- ROI align (7x7 bins, 2x2 samples, avg then channel max) ----------------
__global__ __launch_bounds__(256)
void roi_align_k(const float* __restrict__ feats, const float* __restrict__ rois,
                 float* __restrict__ roi_feats)
{
    __shared__ int s_o00[196], s_o01[196], s_o10[196], s_o11[196];
    __shared__ float s_w[4][196];
    const int n = blockIdx.x;       // 0..95
    const int b = n / RR;
    const int t = threadIdx.x;
    if (t < 196) {
        float x1 = rois[n * 4 + 0] * WW, y1 = rois[n * 4 + 1] * HH;
        float x2 = rois[n * 4 + 2] * WW, y2 = rois[n * 4 + 3] * HH;
        float rw = fmaxf(x2 - x1, 1.f), rh = fmaxf(y2 - y1, 1.f);
        float bw = rw / 7.f, bh = rh / 7.f;
        int j = t / 14, i = t % 14;
        float gy = (float)(j >> 1) + ((j & 1) + 0.5f) * 0.5f;
        float gx = (float)(i >> 1) + ((i & 1) + 0.5f) * 0.5f;
        float ys = y1 + gy * bh, xs = x1 + gx * bw;
        bool valid = (ys >= -1.f) && (ys <= (float)HH) && (xs >= -1.f) && (xs <= (float)WW);
        float y = fminf(fmaxf(ys, 0.f), (float)(HH - 1));
        float x = fminf(fmaxf(xs, 0.f), (float)(WW - 1));
        float y0f = floorf(y), x0f = floorf(x);
        int iy0 = (int)y0f, ix0 = (int)x0f;
        int iy1 = min(iy0 + 1, HH - 1), ix1 = min(ix0 + 1, WW - 1);
        float ly = y - y0f, lx = x - x0f, hy = 1.f - ly, hx = 1.f - lx;
        float msk = valid ? 1.f : 0.f;
        s_o00[t] = iy0 * WW + ix0; s_o01[t] = iy0 * WW + ix1;
        s_o10[t] = iy1 * WW + ix0; s_o11[t] = iy1 * WW + ix1;
        s_w[0][t] = hy * hx * msk; s_w[1][t] = hy * lx * msk;
        s_w[2][t] = ly * hx * msk; s_w[3][t] = ly * lx * msk;
    }
    __syncthreads();
    for (int c = t; c < REDUCE; c += 256) {
        const float* img = feats + ((long)(b * REDUCE + c)) * HWIN;
        float mx = -INFINITY;
        for (int bin = 0; bin < 49; ++bin) {
            int by_ = bin / 7, bx = bin % 7;
            float s = 0.f;
#pragma unroll
            for (int sy = 0; sy < 2; ++sy)
#pragma unroll
                for (int sx = 0; sx < 2; ++sx) {
                    int ss = (by_ * 2 + sy) * 14 + bx * 2 + sx;
                    s += s_w[0][ss] * img[s_o00[ss]] + s_w[1][ss] * img[s_o01[ss]]
                       + s_w[2][ss] * img[s_o10[ss]] + s_w[3][ss] * img[s_o11[ss]];
                }
            mx = fmaxf(mx, s * 0.25f);
        }
        roi_feats[(long)n * REDUCE + c] = mx;
    }
}

// ---------------- small dense dots: Y[n,o] = dot(X[n,:], W[o, woff:woff+K]) ----------------
__global__ void dots_k(const float* __restrict__ Xr, const float* __restrict__ Wt,
                       int ldw, int woff, float* __restrict__ Y,
                       int Nrows, int M, int K, int relu)
{
    int idx = blockIdx.x * blockDim.x + threadIdx.x;
    if (idx >= Nrows * M) return;
    int o = idx / Nrows, n = idx % Nrows;   // wave shares o -> scalarizable weight loads
    const float* xr = Xr + (long)n * K;
    const float* w = Wt + (long)o * ldw + woff;
    float acc = 0.f;
    for (int k = 0; k < K; ++k) acc = fmaf(xr[k], w[k], acc);
    if (relu) acc = fmaxf(acc, 0.f);
    Y[(long)n * M + o] = acc;
}

// ---------------- maxpool 3x3 s2 pad1: (96,512,14,27) -> (96,512,7,14) ----------------
__global__ void maxpool_k(const float* __restrict__ in, float* __restrict__ out, int total)
{
    int idx = blockIdx.x * blockDim.x + threadIdx.x;
    if (idx >= total) return;
    int ow = idx % PW; int r = idx / PW; int oh = r % PH; long nc = r / PH;
    const float* src = in + nc * NSP2;
    float m = -INFINITY;
    for (int kh = 0; kh < 3; ++kh) {
        int ih = oh * 2 - 1 + kh; if (ih < 0 || ih >= OH2) continue;
        for (int kw = 0; kw < 3; ++kw) {
            int iw = ow * 2 - 1 + kw; if (iw < 0 || iw >= OW2) continue;
            m = fmaxf(m, src[ih * OW2 + iw]);
        }
    }
    out[idx] = m;
}

// ---------------- attention: raw scores ----------------
__global__ void att_k(const float* __restrict__ q, const float* __restrict__ k,
                      float* __restrict__ att)
{
    int idx = blockIdx.x * blockDim.x + threadIdx.x;
    const int TOT = BB * 144 * 49;
    if (idx >= TOT) return;
    int ph = idx % 49; int r = idx / 49; int ij = r % 144; int b = r / 144;
    int i = ij / 12, j = ij % 12;
    int p = ph * 2;
    const float* qp = q + ((long)(b * RR + i) * HID) * NSP + p;
    const float* kp = k + ((long)(b * RR + j) * HID) * NSP + p;
    float a0 = 0.f, a1 = 0.f;
#pragma unroll 8
    for (int c = 0; c < HID; ++c) {
        float2 q2 = *(const float2*)(qp + (long)c * NSP);
        float2 k2 = *(const float2*)(kp + (long)c * NSP);
        a0 = fmaf(q2.x, k2.x, a0);
        a1 = fmaf(q2.y, k2.y, a1);
    }
    float* op = att + (((long)(b * 12 + i)) * 12 + j) * NSP + p;
    op[0] = a0 * ATT_SCALE;
    op[1] = a1 * ATT_SCALE;
}

// ---------------- softmax over j ----------------
__global__ void softmax_k(float* __restrict__ att)
{
    int idx = blockIdx.x * blockDim.x + threadIdx.x;
    const int TOT = BB * 12 * NSP;
    if (idx >= TOT) return;
    int p = idx % NSP; int r = idx / NSP; int i = r % 12; int b = r / 12;
    float* base = att + ((long)(b * 12 + i) * 12) * NSP + p;
    float v[12]; float m = -INFINITY;
#pragma unroll
    for (int j = 0; j < 12; ++j) { v[j] = base[j * NSP]; m = fmaxf(m, v[j]); }
    float s = 0.f;
#pragma unroll
    for (int j = 0; j < 12; ++j) { v[j] = expf(v[j] - m); s += v[j]; }
    float inv = 1.f / s;
#pragma unroll
    for (int j = 0; j < 12; ++j) base[j * NSP] = v[j] * inv;
}

// ---------------- virt = att @ v ----------------
__global__ void virt_k(const float* __restrict__ att, const float* __restrict__ v,
                       float* __restrict__ virt)
{
    int idx = blockIdx.x * blockDim.x + threadIdx.x;
    const int TOT = BB * RR * HID * 49;
    if (idx >= TOT) return;
    int ph = idx % 49; int r = idx / 49; int c = r % HID; int r2 = r / HID;
    int i = r2 % RR; int b = r2 / RR;
    int p = 2 * ph;
    const float* ap = att + ((long)(b * 12 + i) * 12) * NSP + p;
    float a0 = 0.f, a1 = 0.f;
#pragma unroll
    for (int j = 0; j < 12; ++j) {
        float w0 = ap[j * NSP], w1 = ap[j * NSP + 1];
        float2 v2 = *(const float2*)(v + (((long)(b * RR + j) * HID) + c) * NSP + p);
        a0 = fmaf(w0, v2.x, a0);
        a1 = fmaf(w1, v2.y, a1);
    }
    float* op = virt + (((long)(b * RR + i) * HID) + c) * NSP + p;
    op[0] = a0; op[1] = a1;
}

// ---------------- per-actor mean/var over (c,h,w) ----------------
__global__ __launch_bounds__(256)
void stats_k(const float* __restrict__ virt, float* __restrict__ mu, float* __restrict__ rstd)
{
    int n = blockIdx.x;
    const float* src = virt + (long)n * HID * NSP;
    float s = 0.f, q = 0.f;
    for (int i = threadIdx.x; i < HID * NSP; i += 256) {
        float v = src[i]; s += v; q = fmaf(v, v, q);
    }
    for (int off = 32; off; off >>= 1) { s += __shfl_down(s, off); q += __shfl_down(q, off); }
    __shared__ float ss[4], sq[4];
    int w = threadIdx.x >> 6;
    if ((threadIdx.x & 63) == 0) { ss[w] = s; sq[w] = q; }
    __syncthreads();
    if (threadIdx.x == 0) {
        float S = ss[0] + ss[1] + ss[2] + ss[3];
        float Q = sq[0] + sq[1] + sq[2] + sq[3];
        const float invN = 1.f / (HID * NSP);
        float m = S * invN;
        float var = Q * invN - m * m;
        mu[n] = m; rstd[n] = rsqrtf(var + 1e-5f);
    }
}

// ---------------- normalize + affine + relu (in place) ----------------
__global__ void norm_k(float* __restrict__ virt, const float* __restrict__ mu,
                       const float* __restrict__ rstd,
                       const float* __restrict__ gamma, const float* __restrict__ beta)
{
    int idx = blockIdx.x * blockDim.x + threadIdx.x;
    const int TOT = NIMG * HID * NSP;
    if (idx >= TOT) return;
    int n = idx / (HID * NSP);
    int c = (idx / NSP) % HID;
    float val = (virt[idx] - mu[n]) * rstd[n] * gamma[c] + beta[c];
    virt[idx] = fmaxf(val, 0.f);
}

// ---------------- spatial mean -> high ----------------
__global__ void meanpool_k(const float* __restrict__ x, float* __restrict__ high)
{
    int idx = blockIdx.x * blockDim.x + threadIdx.x;
    if (idx >= NIMG * HID) return;
    const float* src = x + (long)idx * NSP;
    float s = 0.f;
    for (int p = 0; p < NSP; ++p) s += src[p];
    high[idx] = s * (1.f / NSP);
}

// ---------------- final: [relu(rf@fc1^T) | high] @ fc2^T ----------------
__global__ void final_k(const float* __restrict__ fc1o, const float* __restrict__ high,
                        const float* __restrict__ fc2, float* __restrict__ out)
{
    int idx = blockIdx.x * blockDim.x + threadIdx.x;
    if (idx >= NIMG * NC) return;
    int n = idx / NC, o = idx % NC;
    const float* w = fc2 + (long)o * (2 * HID);
    const float* a = fc1o + (long)n * HID;
    const float* h = high + (long)n * HID;
    float acc = 0.f;
    for (int c = 0; c < HID; ++c) acc = fmaf(a[c], w[c], acc);
    for (int c = 0; c < HID; ++c) acc = fmaf(h[c], w[HID + c], acc);
    out[idx] = acc;
}

// ---------------- launcher ----------------
extern "C" void kernel_launch(void* const* d_in, const int* in_sizes, int n_in,
                              void* d_out, int out_size, void* d_ws, size_t ws_size,
                              hipStream_t stream)
{
    (void)in_sizes; (void)n_in; (void)out_size; (void)ws_size;
    const float* features = (const float*)d_in[0];
    const float* rois     = (const float*)d_in[1];
    const float* w_reduce = (const float*)d_in[2];
    const float* w_conv1  = (const float*)d_in[3];
    const float* w_conv2  = (const float*)d_in[4];
    const float* qw       = (const float*)d_in[5];
    const float* kw       = (const float*)d_in[6];
    const float* vw       = (const float*)d_in[7];
    const float* cw       = (const float*)d_in[8];
    const float* gamma    = (const float*)d_in[9];
    const float* beta     = (const float*)d_in[10];
    const float* fc1      = (const float*)d_in[11];
    const float* fc2      = (const float*)d_in[12];
    float* ws = (float*)d_ws;

    // workspace layout (floats); total 34,273,728 floats = 137.1 MB
    // region [0, 18579456): tmean (stage 1-2) / out2 (stage 6-7) / q,k,v (hr2o)
    float* tmean = ws + 0;                 // 8*2304*464   = 8,552,448
    float* out2  = ws + 0;                 // 96*512*378   = 18,579,456
    float* qb    = ws + 0;                 // 96*512*98    = 4,816,896
    float* kb    = ws + 4816896;
    float* vb    = ws + 9633792;
    float* feats = ws + 18579456;          // 8*1024*464   = 3,801,088
    float* virt  = ws + 22380544;          // 4,816,896
    float* xb    = ws + 27197440;          // 4,816,896
    float* bg    = ws + 32014336;          // 8*512*464    = 1,900,544
    float* rf    = ws + 33914880;          // 96*1024
    float* bias1 = ws + 34013184;          // 96*512
    float* fc1o  = ws + 34062336;          // 96*512
    float* attb  = ws + 34111488;          // 8*12*12*98   = 112,896
    float* mu    = ws + 34224384;          // 96
    float* rstd  = ws + 34224480;          // 96
    float* high  = ws + 34224576;          // 96*512

    dim3 blk(256);

    // 1. temporal mean over T=4
    { int tot = BB * WIDTH * HWIN;
      tmean_k<<<(tot + 255) / 256, blk, 0, stream>>>(features, tmean, tot); }

    // 2. 1x1 reduce conv: feats[b] = W(1024x2304) @ tmean[b]
    gemm_k<0, false, false><<<dim3(4, 8, 8), blk, 0, stream>>>(
        w_reduce, nullptr, nullptr, 2304,
        tmean, (long)WIDTH * HWIN, nullptr, nullptr,
        feats, nullptr, nullptr, 1024, HWIN, 2304);

    // 3. ROI align + channel max
    roi_align_k<<<96, blk, 0, stream>>>(feats, rois, rf);

    // 4. actor bias (conv1 cols 1024..2047) and fc1
    dots_k<<<(NIMG * HID + 255) / 256, blk, 0, stream>>>(rf, w_conv1, 2048, 1024, bias1, NIMG, HID, REDUCE, 0);
    dots_k<<<(NIMG * HID + 255) / 256, blk, 0, stream>>>(rf, fc1, 1024, 0, fc1o, NIMG, HID, REDUCE, 1);

    // 5. bg part of conv1 (shared across R=12 rois per batch)
    gemm_k<0, false, false><<<dim3(4, 4, 8), blk, 0, stream>>>(
        w_conv1, nullptr, nullptr, 2048,
        feats, (long)REDUCE * HWIN, nullptr, nullptr,
        bg, nullptr, nullptr, HID, HWIN, REDUCE);

    // 6. conv2 (3x3 valid) with fused concat+bias+relu input, relu output
    gemm_k<1, true, false><<<dim3(3, 4, 96), blk, 0, stream>>>(
        w_conv2, nullptr, nullptr, 4608,
        bg, 0, bias1, nullptr,
        out2, nullptr, nullptr, HID, NSP2, 4608);

    // 7. maxpool -> x (96,512,7,14)
    { int tot = NIMG * HID * NSP;
      maxpool_k<<<(tot + 255) / 256, blk, 0, stream>>>(out2, xb, tot); }

    // 8. HR2O layers
    for (int d = 0; d < DEPTH; ++d) {
        long woff = (long)d * HID * HID * 9;
        gemm_k<3, false, false><<<dim3(1, 12, 96), blk, 0, stream>>>(
            qw + woff, kw + woff, vw + woff, 4608,
            xb, 0, nullptr, nullptr,
            qb, kb, vb, HID, NSP, 4608);
        { int tot = BB * 144 * 49;
          att_k<<<(tot + 255) / 256, blk, 0, stream>>>(qb, kb, attb); }
        { int tot = BB * 12 * NSP;
          softmax_k<<<(tot + 255) / 256, blk, 0, stream>>>(attb); }
        { int tot = BB * RR * HID * 49;
          virt_k<<<(tot + 255) / 256, blk, 0, stream>>>(attb, vb, virt); }
        stats_k<<<96, blk, 0, stream>>>(virt, mu, rstd);
        { int tot = NIMG * HID * NSP;
          norm_k<<<(tot + 255) / 256, blk, 0, stream>>>(virt, mu, rstd, gamma + d * HID, beta + d * HID); }
        gemm_k<2, false, true><<<dim3(1, 4, 96), blk, 0, stream>>>(
            cw + woff, nullptr, nullptr, 4608,
            virt, 0, nullptr, xb,
            xb, nullptr, nullptr, HID, NSP, 4608);
    }

    // 9. spatial mean -> high
    meanpool_k<<<(NIMG * HID + 255) / 256, blk, 0, stream>>>(xb, high);

    // 10. final FC
    final_k<<<(NIMG * NC + 255) / 256, blk, 0, stream>>>(fc1o, high, fc2, (float*)d_out);
}

// Round 2
// 4427.031 us; speedup vs baseline: 2.8968x; 2.8968x over previous
//
#include <hip/hip_runtime.h>
#include <math.h>

// ---------------- problem dims ----------------
#define BB 8
#define RR 12
#define WIDTH 2304
#define TT 4
#define HH 16
#define WW 29
#define HWIN (HH*WW)        // 464
#define REDUCE 1024
#define HID 512
#define NC 60
#define DEPTH 2
#define NIMG (BB*RR)        // 96
#define OH2 14
#define OW2 27
#define NSP2 (OH2*OW2)      // 378
#define PH 7
#define PW 14
#define NSP (PH*PW)         // 98
#define ATT_SCALE 0.044194173824159216f

typedef __attribute__((ext_vector_type(8))) short short8;
typedef __attribute__((ext_vector_type(4))) float floatx4;

// ---------------- helpers ----------------
__device__ __forceinline__ void split2(float v, unsigned short& h, unsigned short& l)
{
    union { float f; unsigned u; } c; c.f = v;
    unsigned hb = c.u & 0xffff0000u;
    h = (unsigned short)(hb >> 16);
    union { float f; unsigned u; } hc; hc.u = hb;
    float r = v - hc.f;
    union { float f; unsigned u; } rc; rc.f = r;
    unsigned ru = rc.u + 0x7fffu + ((rc.u >> 16) & 1u);
    l = (unsigned short)(ru >> 16);
}

__device__ __forceinline__ void gll16(const void* g, void* l)
{
    __builtin_amdgcn_global_load_lds((const __attribute__((address_space(1))) void*)g,
                                     (__attribute__((address_space(3))) void*)l,
                                     16, 0, 0);
}

// ---------------- split-bf16 MFMA tap-ordered implicit-GEMM conv ----------------
// Weights pre-tiled: [K'/8=576][512][8] bf16, hi plane then lo plane (+294912 int4 units).
// K' = tap*512 + ci. B: fp32 padded plane, contiguous shifted load, hi/lo split on the fly.
// TYPE 0: hr2o conv (xpad 9x16 plane, out [512][98], mask ow<14)
// TYPE 1: conv2 (bg + bias + relu on the fly, 16x29 plane, out [512][378], mask ow<27)
#define TG_BM 256

template<int TYPE, bool RELU, bool RESID, int NSEL>
__global__ __launch_bounds__(256, 2)
void tapgemm_k(const int4* __restrict__ WH0, const int4* __restrict__ WH1, const int4* __restrict__ WH2,
               const float* __restrict__ plane, const float* __restrict__ bias,
               const float* __restrict__ Res,
               float* __restrict__ Y0, float* __restrict__ Y1, float* __restrict__ Y2)
{
    __shared__ int4 L[2960];   // AsHi[0,1028) AsLo[1028,2056) BsHi[2056,2508) BsLo[2508,2960)
    const int tid = threadIdx.x;
    const int z = blockIdx.z;
    const int nb = blockIdx.x;
    int by = blockIdx.y;

    const int4* WH = WH0;
    float* Y = Y0;
    if (NSEL == 3) {
        int sel = by >> 1; by &= 1;
        if (sel == 1) { WH = WH1; Y = Y1; }
        else if (sel == 2) { WH = WH2; Y = Y2; }
    }
    const int m0 = by * TG_BM;
    const int lane = tid & 63;
    const int wv = tid >> 6;
    const int lrow = lane >> 4, lcol = lane & 15;

    // B loader per-thread constants
    const int PS = (TYPE == 0) ? 144 : 464;
    int nA[2], gA[2], pbA[2]; bool vA[2];
#pragma unroll
    for (int it = 0; it < 2; ++it) {
        int u = tid + (it << 8);
        vA[it] = (u < 448);
        int uu = vA[it] ? u : 0;
        nA[it] = uu % 112; gA[it] = uu / 112;
        if (TYPE == 0) pbA[it] = nA[it];
        else { int gn = nb * 112 + nA[it]; pbA[it] = (gn >> 5) * 29 + (gn & 31); }
    }

    const float* planeZ = (TYPE == 0) ? plane + (size_t)z * (512 * 144)
                                      : plane + (size_t)(z / RR) * (512 * 464);
    const float* biasZ = (TYPE == 1) ? bias + z * 512 : nullptr;

    floatx4 acc[4][7];
#pragma unroll
    for (int mf = 0; mf < 4; ++mf)
#pragma unroll
        for (int nf = 0; nf < 7; ++nf) acc[mf][nf] = (floatx4){0.f, 0.f, 0.f, 0.f};

    const int mch = tid & 192;   // wave-uniform chunk base

    for (int kst = 0; kst < 144; ++kst) {
        const int tap = kst >> 4;
        const int ci0 = (kst & 15) << 5;
        const int k8 = kst << 2;
        const int t3 = tap / 3;
        const int shv = (TYPE == 0) ? (t3 * 16 + (tap - t3 * 3)) : (t3 * 29 + (tap - t3 * 3));

        // ---- stage A: global_load_lds 16B, hi + lo planes ----
#pragma unroll
        for (int g = 0; g < 4; ++g) {
            gll16(WH + (size_t)(k8 + g) * 512 + m0 + tid, L + (g * 257 + mch));
            gll16(WH + 294912 + (size_t)(k8 + g) * 512 + m0 + tid, L + (1028 + g * 257 + mch));
        }
        // ---- stage B: fp32 load, hi/lo split, ds_write_b128 ----
#pragma unroll
        for (int it = 0; it < 2; ++it) {
            if (vA[it]) {
                const int g = gA[it];
                const int cb = ci0 + (g << 3);
                const float* src = planeZ + (size_t)cb * PS + pbA[it] + shv;
                float v[8];
#pragma unroll
                for (int i = 0; i < 8; ++i) v[i] = src[(size_t)i * PS];
                if (TYPE == 1) {
#pragma unroll
                    for (int i = 0; i < 8; ++i) v[i] = fmaxf(v[i] + biasZ[cb + i], 0.f);
                }
                unsigned hw[4], lw[4];
#pragma unroll
                for (int j = 0; j < 4; ++j) {
                    unsigned short h0, l0, h1, l1;
                    split2(v[2 * j], h0, l0);
                    split2(v[2 * j + 1], h1, l1);
                    hw[j] = (unsigned)h0 | ((unsigned)h1 << 16);
                    lw[j] = (unsigned)l0 | ((unsigned)l1 << 16);
                }
                L[2056 + g * 113 + nA[it]] = make_int4(hw[0], hw[1], hw[2], hw[3]);
                L[2508 + g * 113 + nA[it]] = make_int4(lw[0], lw[1], lw[2], lw[3]);
            }
        }
        __syncthreads();   // staging visible (compiler drains vmcnt for gll)

        // ---- compute ----
        short8 ah[4], al[4];
#pragma unroll
        for (int mf = 0; mf < 4; ++mf) {
            int au = lrow * 257 + ((wv << 2) + mf) * 16 + lcol;
            ah[mf] = *((const short8*)(L + au));
            al[mf] = *((const short8*)(L + 1028 + au));
        }
#pragma unroll
        for (int nf = 0; nf < 7; ++nf) {
            int bu = 2056 + lrow * 113 + (nf << 4) + lcol;
            short8 bh = *((const short8*)(L + bu));
            short8 bl = *((const short8*)(L + bu + 452));
#pragma unroll
            for (int mf = 0; mf < 4; ++mf) {
                acc[mf][nf] = __builtin_amdgcn_mfma_f32_16x16x32_bf16(ah[mf], bh, acc[mf][nf], 0, 0, 0);
                acc[mf][nf] = __builtin_amdgcn_mfma_f32_16x16x32_bf16(ah[mf], bl, acc[mf][nf], 0, 0, 0);
                acc[mf][nf] = __builtin_amdgcn_mfma_f32_16x16x32_bf16(al[mf], bh, acc[mf][nf], 0, 0, 0);
            }
        }
        __syncthreads();   // compute done before next stage overwrites
    }

    // ---- epilogue: masked store, optional residual/relu ----
#pragma unroll
    for (int mf = 0; mf < 4; ++mf) {
        int mrow = m0 + (wv << 6) + (mf << 4) + (lrow << 2);
#pragma unroll
        for (int nf = 0; nf < 7; ++nf) {
            int col = (nf << 4) + lcol;
            int sp, realn; bool ok;
            if (TYPE == 0) {
                int oh = col >> 4, ow = col & 15;
                ok = (ow < 14); sp = oh * 14 + ow; realn = 98;
            } else {
                int gn = nb * 112 + col;
                int oh = gn >> 5, ow = gn & 31;
                ok = (ow < 27); sp = oh * 27 + ow; realn = 378;
            }
            if (ok) {
#pragma unroll
                for (int r = 0; r < 4; ++r) {
                    size_t idx = ((size_t)z * 512 + mrow + r) * realn + sp;
                    float val = acc[mf][nf][r];
                    if (RESID) val += Res[idx];
                    if (RELU) val = fmaxf(val, 0.f);
                    Y[idx] = val;
                }
            }
        }
    }
}

// ---------------- weight prep: fp32 [512][ci*9+tap] -> tiled bf16 hi/lo [576][512][8], k'=tap*512+ci ----
__global__ void prep_w_k(const float* __restrict__ s0, const float* __restrict__ s1,
                         const float* __restrict__ s2, const float* __restrict__ s3,
                         int4* __restrict__ dst)
{
    const int c = blockIdx.y;
    const float* src = (c == 0) ? s0 : (c == 1) ? s1 : (c == 2) ? s2 : s3;
    int4* dh = dst + (size_t)c * 589824;
    int4* dl = dh + 294912;
    int idx = blockIdx.x * 256 + threadIdx.x;
    if (idx >= 294912) return;
    int g8 = idx / 512, m = idx & 511;
    unsigned hw[4], lw[4];
#pragma unroll
    for (int j = 0; j < 4; ++j) {
        int k1 = g8 * 8 + 2 * j, k2 = k1 + 1;
        float v1 = src[(size_t)m * 4608 + ((k1 & 511) * 9 + (k1 >> 9))];
        float v2 = src[(size_t)m * 4608 + ((k2 & 511) * 9 + (k2 >> 9))];
        unsigned short h0, l0, h1, l1;
        split2(v1, h0, l0); split2(v2, h1, l1);
        hw[j] = (unsigned)h0 | ((unsigned)h1 << 16);
        lw[j] = (unsigned)l0 | ((unsigned)l1 << 16);
    }
    dh[idx] = make_int4(hw[0], hw[1], hw[2], hw[3]);
    dl[idx] = make_int4(lw[0], lw[1], lw[2], lw[3]);
}

// ---------------- zero-pad 7x14 -> 9x16 plane ----------------
__global__ void pad_k(const float* __restrict__ x, float* __restrict__ xp, int total)
{
    int idx = blockIdx.x * blockDim.x + threadIdx.x;
    if (idx >= total) return;
    int p = idx % 144; int cn = idx / 144;
    int row = p >> 4, col = p & 15;
    float v = 0.f;
    if (row >= 1 && row <= 7 && col >= 1 && col <= 14)
        v = x[(size_t)cn * 98 + (row - 1) * 14 + (col - 1)];
    xp[idx] = v;
}

// ---------------- fp32 tiled GEMM (reduce conv / bg part) ----------------
#define TS 128
#define KC 8
__global__ __launch_bounds__(256)
void gemm32_k(const float* __restrict__ A, int lda,
              const float* __restrict__ Bm, long bstride,
              float* __restrict__ Y, int M, int N, int K)
{
    __shared__ float As[KC][TS + 4];
    __shared__ float Bs[KC][TS + 4];
    const int tid = threadIdx.x;
    const int tx = tid & 15, ty = tid >> 4;
    const int n0 = blockIdx.x * TS;
    const int m0 = blockIdx.y * TS;
    const int z = blockIdx.z;
    const int a_k = tid & (KC - 1);
    const int a_m0 = tid >> 3;
    const int b_n = tid & (TS - 1);
    const int b_k0 = tid >> 7;

    float acc[8][8];
#pragma unroll
    for (int i = 0; i < 8; ++i)
#pragma unroll
        for (int j = 0; j < 8; ++j) acc[i][j] = 0.f;

    for (int k0 = 0; k0 < K; k0 += KC) {
#pragma unroll
        for (int r = 0; r < 4; ++r) {
            int m = a_m0 + r * 32;
            As[a_k][m] = A[(long)(m0 + m) * lda + (k0 + a_k)];
        }
#pragma unroll
        for (int r = 0; r < 4; ++r) {
            int kk = b_k0 * 4 + r;
            int n = n0 + b_n;
            float v = 0.f;
            if (n < N) v = Bm[(long)z * bstride + (long)(k0 + kk) * N + n];
            Bs[kk][b_n] = v;
        }
        __syncthreads();
#pragma unroll
        for (int kk = 0; kk < KC; ++kk) {
            float a[8], b[8];
#pragma unroll
            for (int i = 0; i < 8; ++i) a[i] = As[kk][ty * 8 + i];
#pragma unroll
            for (int j = 0; j < 8; ++j) b[j] = Bs[kk][tx * 8 + j];
#pragma unroll
            for (int i = 0; i < 8; ++i)
#pragma unroll
                for (int j = 0; j < 8; ++j) acc[i][j] = fmaf(a[i], b[j], acc[i][j]);
        }
        __syncthreads();
    }
#pragma unroll
    for (int i = 0; i < 8; ++i) {
        int m = m0 + ty * 8 + i;
#pragma unroll
        for (int j = 0; j < 8; ++j) {
            int n = n0 + tx * 8 + j;
            if (n < N) Y[((long)z * M + m) * N + n] = acc[i][j];
        }
    }
}

// ---------------- temporal mean ----------------
__global__ void tmean_k(const float* __restrict__ f, float* __restrict__ o, int total)
{
    int i = blockIdx.x * blockDim.x + threadIdx.x;
    if (i >= total) return;
    int p = i % HWIN; long bc = i / HWIN;
    const float* src = f + bc * (long)TT * HWIN + p;
    o[i] = (src[0] + src[HWIN] + src[2 * HWIN] + src[3 * HWIN]) * 0.25f;
}

// ---------------- ROI align ----------------
__global__ __launch_bounds__(256)
void roi_align_k(const float* __restrict__ feats, const float* __restrict__ rois,
                 float* __restrict__ roi_feats)
{
    __shared__ int s_o00[196], s_o01[196], s_o10[196], s_o11[196];
    __shared__ float s_w[4][196];
    const int n = blockIdx.x;
    const int b = n / RR;
    const int t = threadIdx.x;
    if (t < 196) {
        float x1 = rois[n * 4 + 0] * WW, y1 = rois[n * 4 + 1] * HH;
        float x2 = rois[n * 4 + 2] * WW, y2 = rois[n * 4 + 3] * HH;
        float rw = fmaxf(x2 - x1, 1.f), rh = fmaxf(y2 - y1, 1.f);
        float bw = rw / 7.f, bh = rh / 7.f;
        int j = t / 14, i = t % 14;
        float gy = (float)(j >> 1) + ((j & 1) + 0.5f) * 0.5f;
        float gx = (float)(i >> 1) + ((i & 1) + 0.5f) * 0.5f;
        float ys = y1 + gy * bh, xs = x1 + gx * bw;
        bool valid = (ys >= -1.f) && (ys <= (float)HH) && (xs >= -1.f) && (xs <= (float)WW);
        float y = fminf(fmaxf(ys, 0.f), (float)(HH - 1));
        float x = fminf(fmaxf(xs, 0.f), (float)(WW - 1));
        float y0f = floorf(y), x0f = floorf(x);
        int iy0 = (int)y0f, ix0 = (int)x0f;
        int iy1 = min(iy0 + 1, HH - 1), ix1 = min(ix0 + 1, WW - 1);
        float ly = y - y0f, lx = x - x0f, hy = 1.f - ly, hx = 1.f - lx;
        float msk = valid ? 1.f : 0.f;
        s_o00[t] = iy0 * WW + ix0; s_o01[t] = iy0 * WW + ix1;
        s_o10[t] = iy1 * WW + ix0; s_o11[t] = iy1 * WW + ix1;
        s_w[0][t] = hy * hx * msk; s_w[1][t] = hy * lx * msk;
        s_w[2][t] = ly * hx * msk; s_w[3][t] = ly * lx * msk;
    }
    __syncthreads();
    for (int c = t; c < REDUCE; c += 256) {
        const float* img = feats + ((long)(b * REDUCE + c)) * HWIN;
        float mx = -INFINITY;
        for (int bin = 0; bin < 49; ++bin) {
            int by_ = bin / 7, bx = bin % 7;
            float s = 0.f;
#pragma unroll
            for (int sy = 0; sy < 2; ++sy)
#pragma unroll
                for (int sx = 0; sx < 2; ++sx) {
                    int ss = (by_ * 2 + sy) * 14 + bx * 2 + sx;
                    s += s_w[0][ss] * img[s_o00[ss]] + s_w[1][ss] * img[s_o01[ss]]
                       + s_w[2][ss] * img[s_o10[ss]] + s_w[3][ss] * img[s_o11[ss]];
                }
            mx = fmaxf(mx, s * 0.25f);
        }
        roi_feats[(long)n * REDUCE + c] = mx;
    }
}

// ---------------- small dense dots ----------------
__global__ void dots_k(const float* __restrict__ Xr, const float* __restrict__ Wt,
                       int ldw, int woff, float* __restrict__ Y,
                       int Nrows, int M, int K, int relu)
{
    int idx = blockIdx.x * blockDim.x + threadIdx.x;
    if (idx >= Nrows * M) return;
    int o = idx / Nrows, n = idx % Nrows;
    const float* xr = Xr + (long)n * K;
    const float* w = Wt + (long)o * ldw + woff;
    float acc = 0.f;
    for (int k = 0; k < K; ++k) acc = fmaf(xr[k], w[k], acc);
    if (relu) acc = fmaxf(acc, 0.f);
    Y[(long)n * M + o] = acc;
}

// ---------------- maxpool 3x3 s2 pad1 ----------------
__global__ void maxpool_k(const float* __restrict__ in, float* __restrict__ out, int total)
{
    int idx = blockIdx.x * blockDim.x + threadIdx.x;
    if (idx >= total) return;
    int ow = idx % PW; int r = idx / PW; int oh = r % PH; long nc = r / PH;
    const float* src = in + nc * NSP2;
    float m = -INFINITY;
    for (int kh = 0; kh < 3; ++kh) {
        int ih = oh * 2 - 1 + kh; if (ih < 0 || ih >= OH2) continue;
        for (int kw = 0; kw < 3; ++kw) {
            int iw = ow * 2 - 1 + kw; if (iw < 0 || iw >= OW2) continue;
            m = fmaxf(m, src[ih * OW2 + iw]);
        }
    }
    out[idx] = m;
}

// ---------------- attention raw scores ----------------
__global__ void att_k(const float* __restrict__ q, const float* __restrict__ k,
                      float* __restrict__ att)
{
    int idx = blockIdx.x * blockDim.x + threadIdx.x;
    const int TOT = BB * 144 * 49;
    if (idx >= TOT) return;
    int ph = idx % 49; int r = idx / 49; int ij = r % 144; int b = r / 144;
    int i = ij / 12, j = ij % 12;
    int p = ph * 2;
    const float* qp = q + ((long)(b * RR + i) * HID) * NSP + p;
    const float* kp = k + ((long)(b * RR + j) * HID) * NSP + p;
    float a0 = 0.f, a1 = 0.f;
#pragma unroll 8
    for (int c = 0; c < HID; ++c) {
        float2 q2 = *(const float2*)(qp + (long)c * NSP);
        float2 k2 = *(const float2*)(kp + (long)c * NSP);
        a0 = fmaf(q2.x, k2.x, a0);
        a1 = fmaf(q2.y, k2.y, a1);
    }
    float* op = att + (((long)(b * 12 + i)) * 12 + j) * NSP + p;
    op[0] = a0 * ATT_SCALE;
    op[1] = a1 * ATT_SCALE;
}

// ---------------- softmax over j ----------------
__global__ void softmax_k(float* __restrict__ att)
{
    int idx = blockIdx.x * blockDim.x + threadIdx.x;
    const int TOT = BB * 12 * NSP;
    if (idx >= TOT) return;
    int p = idx % NSP; int r = idx / NSP; int i = r % 12; int b = r / 12;
    float* base = att + ((long)(b * 12 + i) * 12) * NSP + p;
    float v[12]; float m = -INFINITY;
#pragma unroll
    for (int j = 0; j < 12; ++j) { v[j] = base[j * NSP]; m = fmaxf(m, v[j]); }
    float s = 0.f;
#pragma unroll
    for (int j = 0; j < 12; ++j) { v[j] = expf(v[j] - m); s += v[j]; }
    float inv = 1.f / s;
#pragma unroll
    for (int j = 0; j < 12; ++j) base[j * NSP] = v[j] * inv;
}

// ---------------- virt = att @ v ----------------
__global__ void virt_k(const float* __restrict__ att, const float* __restrict__ v,
                       float* __restrict__ virt)
{
    int idx = blockIdx.x * blockDim.x + threadIdx.x;
    const int TOT = BB * RR * HID * 49;
    if (idx >= TOT) return;
    int ph = idx % 49; int r = idx / 49; int c = r % HID; int r2 = r / HID;
    int i = r2 % RR; int b = r2 / RR;
    int p = 2 * ph;
    const float* ap = att + ((long)(b * 12 + i) * 12) * NSP + p;
    float a0 = 0.f, a1 = 0.f;
#pragma unroll
    for (int j = 0; j < 12; ++j) {
        float w0 = ap[j * NSP], w1 = ap[j * NSP + 1];
        float2 v2 = *(const float2*)(v + (((long)(b * RR + j) * HID) + c) * NSP + p);
        a0 = fmaf(w0, v2.x, a0);
        a1 = fmaf(w1, v2.y, a1);
    }
    float* op = virt + (((long)(b * RR + i) * HID) + c) * NSP + p;
    op[0] = a0; op[1] = a1;
}

// ---------------- per-actor stats ----------------
__global__ __launch_bounds__(256)
void stats_k(const float* __restrict__ virt, float* __restrict__ mu, float* __restrict__ rstd)
{
    int n = blockIdx.x;
    const float* src = virt + (long)n * HID * NSP;
    float s = 0.f, q = 0.f;
    for (int i = threadIdx.x; i < HID * NSP; i += 256) {
        float v = src[i]; s += v; q = fmaf(v, v, q);
    }
    for (int off = 32; off; off >>= 1) { s += __shfl_down(s, off); q += __shfl_down(q, off); }
    __shared__ float ss[4], sq[4];
    int w = threadIdx.x >> 6;
    if ((threadIdx.x & 63) == 0) { ss[w] = s; sq[w] = q; }
    __syncthreads();
    if (threadIdx.x == 0) {
        float S = ss[0] + ss[1] + ss[2] + ss[3];
        float Q = sq[0] + sq[1] + sq[2] + sq[3];
        const float invN = 1.f / (HID * NSP);
        float m = S * invN;
        float var = Q * invN - m * m;
        mu[n] = m; rstd[n] = rsqrtf(var + 1e-5f);
    }
}

// ---------------- normalize + affine + relu ----------------
__global__ void norm_k(float* __restrict__ virt, const float* __restrict__ mu,
                       const float* __restrict__ rstd,
                       const float* __restrict__ gamma, const float* __restrict__ beta)
{
    int idx = blockIdx.x * blockDim.x + threadIdx.x;
    const int TOT = NIMG * HID * NSP;
    if (idx >= TOT) return;
    int n = idx / (HID * NSP);
    int c = (idx / NSP) % HID;
    float val = (virt[idx] - mu[n]) * rstd[n] * gamma[c] + beta[c];
    virt[idx] = fmaxf(val, 0.f);
}

// ---------------- spatial mean ----------------
__global__ void meanpool_k(const float* __restrict__ x, float* __restrict__ high)
{
    int idx = blockIdx.x * blockDim.x + threadIdx.x;
    if (idx >= NIMG * HID) return;
    const float* src = x + (long)idx * NSP;
    float s = 0.f;
    for (int p = 0; p < NSP; ++p) s += src[p];
    high[idx] = s * (1.f / NSP);
}

// ---------------- final FC ----------------
__global__ void final_k(const float* __restrict__ fc1o, const float* __restrict__ high,
                        const float* __restrict__ fc2, float* __restrict__ out)
{
    int idx = blockIdx.x * blockDim.x + threadIdx.x;
    if (idx >= NIMG * NC) return;
    int n = idx / NC, o = idx % NC;
    const float* w = fc2 + (long)o * (2 * HID);
    const float* a = fc1o + (long)n * HID;
    const float* h = high + (long)n * HID;
    float acc = 0.f;
    for (int c = 0; c < HID; ++c) acc = fmaf(a[c], w[c], acc);
    for (int c = 0; c < HID; ++c) acc = fmaf(h[c], w[HID + c], acc);
    out[idx] = acc;
}

// ---------------- launcher ----------------
extern "C" void kernel_launch(void* const* d_in, const int* in_sizes, int n_in,
                              void* d_out, int out_size, void* d_ws, size_t ws_size,
                              hipStream_t stream)
{
    (void)in_sizes; (void)n_in; (void)out_size; (void)ws_size;
    const float* features = (const float*)d_in[0];
    const float* rois     = (const float*)d_in[1];
    const float* w_reduce = (const float*)d_in[2];
    const float* w_conv1  = (const float*)d_in[3];
    const float* w_conv2  = (const float*)d_in[4];
    const float* qw       = (const float*)d_in[5];
    const float* kw       = (const float*)d_in[6];
    const float* vw       = (const float*)d_in[7];
    const float* cw       = (const float*)d_in[8];
    const float* gamma    = (const float*)d_in[9];
    const float* beta     = (const float*)d_in[10];
    const float* fc1      = (const float*)d_in[11];
    const float* fc2      = (const float*)d_in[12];
    float* ws = (float*)d_ws;

    // ---- workspace layout (floats), total ~63.8M = 255 MB ----
    float* xpad  = ws + 0;         // 96*512*144 = 7,077,888 (+64 slack); reused for vpad
    float* qb    = ws + 7077952;   // 4,816,896
    float* kb    = ws + 11894848;
    float* vb    = ws + 16711744;
    float* virt  = ws + 21528640;
    float* xb    = ws + 26345536;
    float* out2  = ws + 31162432;  // 18,579,456 ; aliases: tmean, feats (dead before conv2)
    float* tmean = out2;                       // 8,552,448
    float* feats = out2 + 8552448;             // 3,801,088
    int4*  WTC2  = (int4*)(ws + 49741888);     // conv2 hi+lo: 589,824 int4 units
    int4*  WTQ   = WTC2 + 589824;              // qkvc (per layer): 4 * 589,824 units
    float* bg    = ws + 61538368;  // 8*512*464 = 1,900,544 (+64 slack)
    float* rf    = ws + 63438976;
    float* bias1 = ws + 63537280;
    float* fc1o  = ws + 63586432;
    float* attb  = ws + 63635584;
    float* mu    = ws + 63748480;
    float* rstd  = ws + 63748576;
    float* high  = ws + 63748672;

    dim3 blk(256);

    // weight prep: conv2 + layer-0 qkvc
    prep_w_k<<<dim3(1152, 1), blk, 0, stream>>>(w_conv2, w_conv2, w_conv2, w_conv2, WTC2);
    prep_w_k<<<dim3(1152, 4), blk, 0, stream>>>(qw, kw, vw, cw, WTQ);

    // 1. temporal mean
    { int tot = BB * WIDTH * HWIN;
      tmean_k<<<(tot + 255) / 256, blk, 0, stream>>>(features, tmean, tot); }

    // 2. 1x1 reduce conv (fp32)
    gemm32_k<<<dim3(4, 8, 8), blk, 0, stream>>>(
        w_reduce, 2304, tmean, (long)WIDTH * HWIN, feats, 1024, HWIN, 2304);

    // 3. ROI align
    roi_align_k<<<96, blk, 0, stream>>>(feats, rois, rf);

    // 4. actor bias + fc1
    dots_k<<<(NIMG * HID + 255) / 256, blk, 0, stream>>>(rf, w_conv1, 2048, 1024, bias1, NIMG, HID, REDUCE, 0);
    dots_k<<<(NIMG * HID + 255) / 256, blk, 0, stream>>>(rf, fc1, 1024, 0, fc1o, NIMG, HID, REDUCE, 1);

    // 5. bg part of conv1 (fp32)
    gemm32_k<<<dim3(4, 4, 8), blk, 0, stream>>>(
        w_conv1, 2048, feats, (long)REDUCE * HWIN, bg, HID, HWIN, REDUCE);

    // 6. conv2: split-bf16 MFMA, fused concat+bias+relu loader, relu epilogue
    tapgemm_k<1, true, false, 1><<<dim3(4, 2, 96), blk, 0, stream>>>(
        WTC2, nullptr, nullptr, bg, bias1, nullptr, out2, nullptr, nullptr);

    // 7. maxpool -> xb
    { int tot = NIMG * HID * NSP;
      maxpool_k<<<(tot + 255) / 256, blk, 0, stream>>>(out2, xb, tot); }

    // 8. HR2O layers
    for (int d = 0; d < DEPTH; ++d) {
        if (d == 1) {
            long woff = (long)HID * HID * 9;
            prep_w_k<<<dim3(1152, 4), blk, 0, stream>>>(qw + woff, kw + woff, vw + woff, cw + woff, WTQ);
        }
        { int tot = NIMG * HID * 144;
          pad_k<<<(tot + 255) / 256, blk, 0, stream>>>(xb, xpad, tot); }

        tapgemm_k<0, false, false, 3><<<dim3(1, 6, 96), blk, 0, stream>>>(
            WTQ, WTQ + 589824, WTQ + 2 * 589824, xpad, nullptr, nullptr, qb, kb, vb);

        { int tot = BB * 144 * 49;
          att_k<<<(tot + 255) / 256, blk, 0, stream>>>(qb, kb, attb); }
        { int tot = BB * 12 * NSP;
          softmax_k<<<(tot + 255) / 256, blk, 0, stream>>>(attb); }
        { int tot = BB * RR * HID * 49;
          virt_k<<<(tot + 255) / 256, blk, 0, stream>>>(attb, vb, virt); }
        stats_k<<<96, blk, 0, stream>>>(virt, mu, rstd);
        { int tot = NIMG * HID * NSP;
          norm_k<<<(tot + 255) / 256, blk, 0, stream>>>(virt, mu, rstd, gamma + d * HID, beta + d * HID); }

        { int tot = NIMG * HID * 144;
          pad_k<<<(tot + 255) / 256, blk, 0, stream>>>(virt, xpad, tot); }

        tapgemm_k<0, false, true, 1><<<dim3(1, 2, 96), blk, 0, stream>>>(
            WTQ + 3 * 589824, nullptr, nullptr, xpad, nullptr, xb, xb, nullptr, nullptr);
    }

    // 9. spatial mean
    meanpool_k<<<(NIMG * HID + 255) / 256, blk, 0, stream>>>(xb, high);

    // 10. final FC
    final_k<<<(NIMG * NC + 255) / 256, blk, 0, stream>>>(fc1o, high, fc2, (float*)d_out);
}

// Round 3
// 3405.362 us; speedup vs baseline: 3.7659x; 1.3000x over previous
//
#include <hip/hip_runtime.h>
#include <math.h>

// ---------------- problem dims ----------------
#define BB 8
#define RR 12
#define WIDTH 2304
#define TT 4
#define HH 16
#define WW 29
#define HWIN (HH*WW)        // 464
#define REDUCE 1024
#define HID 512
#define NC 60
#define DEPTH 2
#define NIMG (BB*RR)        // 96
#define OH2 14
#define OW2 27
#define NSP2 (OH2*OW2)      // 378
#define PH 7
#define PW 14
#define NSP (PH*PW)         // 98
#define ATT_SCALE 0.044194173824159216f

typedef __attribute__((ext_vector_type(8))) short short8;
typedef __attribute__((ext_vector_type(4))) float floatx4;

// ---------------- helpers ----------------
__device__ __forceinline__ void split2(float v, unsigned short& h, unsigned short& l)
{
    union { float f; unsigned u; } c; c.f = v;
    unsigned hb = c.u & 0xffff0000u;
    h = (unsigned short)(hb >> 16);
    union { float f; unsigned u; } hc; hc.u = hb;
    float r = v - hc.f;
    union { float f; unsigned u; } rc; rc.f = r;
    unsigned ru = rc.u + 0x7fffu + ((rc.u >> 16) & 1u);
    l = (unsigned short)(ru >> 16);
}

__device__ __forceinline__ void gll16(const void* g, void* l)
{
    __builtin_amdgcn_global_load_lds((const __attribute__((address_space(1))) void*)g,
                                     (__attribute__((address_space(3))) void*)l,
                                     16, 0, 0);
}

#define MFMA3(d, ah_, al_, bh_, bl_) \
    d = __builtin_amdgcn_mfma_f32_16x16x32_bf16(ah_, bh_, d, 0, 0, 0); \
    d = __builtin_amdgcn_mfma_f32_16x16x32_bf16(ah_, bl_, d, 0, 0, 0); \
    d = __builtin_amdgcn_mfma_f32_16x16x32_bf16(al_, bh_, d, 0, 0, 0);

// ---------------- 2-phase pipelined split-bf16 MFMA implicit-GEMM ----------------
// Weights pre-tiled [K/8][MTOT][8] bf16 (hi plane, then lo plane at +KSTN*4*MTOT int4).
// B prestaged as transposed bf16 hi/lo planes [sp][KW] per z.
// TYPE 0: hr2o pad-1 3x3 conv (plane 160x512 rows, tap-ordered K)
// TYPE 1: conv2 valid 3x3 conv (plane 472x512 rows, tap-ordered K)
// TYPE 2: plain GEMM (no taps), K = KW
// LDS per buffer (int4): A hi g*129 | A lo 516+g*129 | B hi 1032+g*113 | B lo 1484+g*113
template<int TYPE, int NSEL, bool RELU, bool RESID, int KW, int KSTN, int MTOT, long PLSTR, int NREAL>
__global__ __launch_bounds__(256, 2)
void tap2_k(const int4* __restrict__ WA0, const int4* __restrict__ WA1, const int4* __restrict__ WA2,
            const ushort* __restrict__ BH, const ushort* __restrict__ BL,
            const float* __restrict__ Res,
            float* __restrict__ Y0, float* __restrict__ Y1, float* __restrict__ Y2)
{
    __shared__ int4 L[3872];
    const int tid = threadIdx.x;
    const int z = blockIdx.z, nb = blockIdx.x;
    int by = blockIdx.y;

    const int4* WA = WA0; float* Y = Y0;
    if (NSEL == 3) {
        int sel = by >> 2; by &= 3;
        if (sel == 1) { WA = WA1; Y = Y1; }
        else if (sel == 2) { WA = WA2; Y = Y2; }
    }
    const int m0 = by * 128;
    const int lane = tid & 63, wv = tid >> 6;
    const int lrow = lane >> 4, lcol = lane & 15;
    constexpr long ALO = (long)KSTN * 4 * MTOT;

    // B-unit per-thread constants: u = g*112 + n
    int nU[2], gU[2]; long pbU[2]; bool vU[2];
#pragma unroll
    for (int it = 0; it < 2; ++it) {
        int u = tid + (it << 8);
        vU[it] = (u < 448);
        int uu = vU[it] ? u : 0;
        nU[it] = uu % 112; gU[it] = uu / 112;
        if (TYPE == 0) pbU[it] = nU[it];
        else {
            int gn = nb * 112 + nU[it];
            if (TYPE == 1) pbU[it] = (gn >> 5) * 29 + (gn & 31);
            else pbU[it] = min(gn, NREAL - 1);
        }
    }
    const ushort* BHz = BH + (size_t)z * PLSTR;
    const ushort* BLz = BL + (size_t)z * PLSTR;

    floatx4 acc[2][7];
#pragma unroll
    for (int mf = 0; mf < 2; ++mf)
#pragma unroll
        for (int nf = 0; nf < 7; ++nf) acc[mf][nf] = (floatx4){0.f, 0.f, 0.f, 0.f};

    short8 rbh[2], rbl[2];

#define STAGE_ISSUE(KST, BUF) { \
    int k8 = (KST) * 4; \
    _Pragma("unroll") \
    for (int j = 0; j < 4; ++j) { \
        int h = wv * 4 + j, p = h >> 3, g = (h >> 1) & 3, hf = h & 1; \
        gll16(WA + (p ? ALO : 0) + (long)(k8 + g) * MTOT + m0 + hf * 64 + lane, \
              L + (BUF) * 1936 + (p * 4 + g) * 129 + hf * 64); \
    } \
    int tap, ci0, shv; \
    if (TYPE == 2) { tap = 0; ci0 = (KST) << 5; shv = 0; } \
    else { tap = (KST) >> 4; ci0 = ((KST) & 15) << 5; int t3 = tap / 3; \
           shv = (TYPE == 0) ? t3 * 16 + (tap - t3 * 3) : t3 * 29 + (tap - t3 * 3); } \
    _Pragma("unroll") \
    for (int it = 0; it < 2; ++it) if (vU[it]) { \
        size_t o = (size_t)(pbU[it] + shv) * KW + ci0 + gU[it] * 8; \
        rbh[it] = *(const short8*)(BHz + o); \
        rbl[it] = *(const short8*)(BLz + o); \
    } }

#define STAGE_WRITE(BUF) { \
    _Pragma("unroll") \
    for (int it = 0; it < 2; ++it) if (vU[it]) { \
        *((short8*)(L + (BUF) * 1936 + 1032 + gU[it] * 113 + nU[it])) = rbh[it]; \
        *((short8*)(L + (BUF) * 1936 + 1484 + gU[it] * 113 + nU[it])) = rbl[it]; \
    } }

#define COMPUTE(BUF) { \
    const int4* Lc = L + (BUF) * 1936; \
    short8 ah[2], al[2]; \
    _Pragma("unroll") \
    for (int mf = 0; mf < 2; ++mf) { \
        int au = lrow * 129 + (wv * 2 + mf) * 16 + lcol; \
        ah[mf] = *(const short8*)(Lc + au); \
        al[mf] = *(const short8*)(Lc + 516 + au); \
    } \
    _Pragma("unroll") \
    for (int nf = 0; nf < 7; ++nf) { \
        int bu = 1032 + lrow * 113 + nf * 16 + lcol; \
        short8 bh = *(const short8*)(Lc + bu); \
        short8 bl = *(const short8*)(Lc + bu + 452); \
        _Pragma("unroll") \
        for (int mf = 0; mf < 2; ++mf) { MFMA3(acc[mf][nf], ah[mf], al[mf], bh, bl) } \
    } }

    // prologue
    STAGE_ISSUE(0, 0)
    STAGE_WRITE(0)
    __syncthreads();

    int cur = 0;
    for (int kst = 0; kst < KSTN; ++kst) {
        int nxt = cur ^ 1;
        bool more = (kst + 1 < KSTN);
        if (more) STAGE_ISSUE(kst + 1, nxt)
        COMPUTE(cur)
        if (more) { STAGE_WRITE(nxt) __syncthreads(); }
        cur = nxt;
    }

    // epilogue
#pragma unroll
    for (int mf = 0; mf < 2; ++mf) {
        int m = m0 + wv * 32 + mf * 16 + lrow * 4;
#pragma unroll
        for (int nf = 0; nf < 7; ++nf) {
            int col = nf * 16 + lcol;
            int sp, realn; bool ok;
            if (TYPE == 0) { int oh = col >> 4, ow = col & 15; ok = ow < 14; sp = oh * 14 + ow; realn = 98; }
            else if (TYPE == 1) { int gn = nb * 112 + col; int oh = gn >> 5, ow = gn & 31; ok = ow < 27; sp = oh * 27 + ow; realn = 378; }
            else { int gn = nb * 112 + col; ok = gn < NREAL; sp = gn; realn = NREAL; }
            if (ok) {
#pragma unroll
                for (int r = 0; r < 4; ++r) {
                    size_t idx = ((size_t)z * MTOT + m + r) * realn + sp;
                    float v = acc[mf][nf][r];
                    if (RESID) v += Res[idx];
                    if (RELU) v = fmaxf(v, 0.f);
                    Y[idx] = v;
                }
            }
        }
    }
#undef STAGE_ISSUE
#undef STAGE_WRITE
#undef COMPUTE
}

// ---------------- weight prep: tap-reordered 3x3 convs [512][4608] -> [576][512][8] hi/lo ----------------
__global__ void prep_w_k(const float* __restrict__ s0, const float* __restrict__ s1,
                         const float* __restrict__ s2, const float* __restrict__ s3,
                         int4* __restrict__ dst)
{
    const int c = blockIdx.y;
    const float* src = (c == 0) ? s0 : (c == 1) ? s1 : (c == 2) ? s2 : s3;
    int4* dh = dst + (size_t)c * 589824;
    int4* dl = dh + 294912;
    int idx = blockIdx.x * 256 + threadIdx.x;
    if (idx >= 294912) return;
    int g8 = idx / 512, m = idx & 511;
    unsigned hw[4], lw[4];
#pragma unroll
    for (int j = 0; j < 4; ++j) {
        int k1 = g8 * 8 + 2 * j, k2 = k1 + 1;
        float v1 = src[(size_t)m * 4608 + ((k1 & 511) * 9 + (k1 >> 9))];
        float v2 = src[(size_t)m * 4608 + ((k2 & 511) * 9 + (k2 >> 9))];
        unsigned short h0, l0, h1, l1;
        split2(v1, h0, l0); split2(v2, h1, l1);
        hw[j] = (unsigned)h0 | ((unsigned)h1 << 16);
        lw[j] = (unsigned)l0 | ((unsigned)l1 << 16);
    }
    dh[idx] = make_int4(hw[0], hw[1], hw[2], hw[3]);
    dl[idx] = make_int4(lw[0], lw[1], lw[2], lw[3]);
}

// ---------------- weight prep: plain GEMM A [M][ldw] -> [K/8][M][8] hi/lo ----------------
__global__ void prep_wg_k(const float* __restrict__ src, int ldw, int M, int K8,
                          int4* __restrict__ dst)
{
    int idx = blockIdx.x * 256 + threadIdx.x;
    if (idx >= K8 * M) return;
    int g8 = idx / M, m = idx % M;
    unsigned hw[4], lw[4];
#pragma unroll
    for (int j = 0; j < 4; ++j) {
        int k1 = g8 * 8 + 2 * j;
        float v1 = src[(size_t)m * ldw + k1];
        float v2 = src[(size_t)m * ldw + k1 + 1];
        unsigned short h0, l0, h1, l1;
        split2(v1, h0, l0); split2(v2, h1, l1);
        hw[j] = (unsigned)h0 | ((unsigned)h1 << 16);
        lw[j] = (unsigned)l0 | ((unsigned)l1 << 16);
    }
    dst[idx] = make_int4(hw[0], hw[1], hw[2], hw[3]);
    dst[(size_t)K8 * M + idx] = make_int4(lw[0], lw[1], lw[2], lw[3]);
}

// ---------------- transpose + split: src [C][S] fp32 -> dst [S][C] bf16 hi/lo ----------------
__global__ __launch_bounds__(256)
void tsplit_k(const float* __restrict__ src, ushort* __restrict__ dh, ushort* __restrict__ dl,
              int C, int S, long zsrc, long zdst)
{
    __shared__ float t[64][65];
    const int c0 = blockIdx.x * 64, s0 = blockIdx.y * 64, z = blockIdx.z;
    const float* sz = src + (size_t)z * zsrc;
    const int tx = threadIdx.x & 63, ty = threadIdx.x >> 6;
#pragma unroll
    for (int i = 0; i < 16; ++i) {
        int cc = i * 4 + ty;
        int c = c0 + cc, s = s0 + tx;
        t[cc][tx] = (c < C && s < S) ? sz[(size_t)c * S + s] : 0.f;
    }
    __syncthreads();
#pragma unroll
    for (int i = 0; i < 16; ++i) {
        int ss = i * 4 + ty;
        int s = s0 + ss, c = c0 + tx;
        if (s < S && c < C) {
            unsigned short h, l;
            split2(t[tx][ss], h, l);
            size_t o = (size_t)z * zdst + (size_t)s * C + c;
            dh[o] = h; dl[o] = l;
        }
    }
}

// ---------------- conv2 B prestage: relu(bg[b] + bias1[z])^T -> [z][472][512] hi/lo ----------------
__global__ __launch_bounds__(256)
void tsplit_c2_k(const float* __restrict__ bg, const float* __restrict__ bias1,
                 ushort* __restrict__ dh, ushort* __restrict__ dl)
{
    __shared__ float t[64][65];
    const int c0 = blockIdx.x * 64, s0 = blockIdx.y * 64, z = blockIdx.z;
    const int b = z / RR;
    const int tx = threadIdx.x & 63, ty = threadIdx.x >> 6;
#pragma unroll
    for (int i = 0; i < 16; ++i) {
        int cc = i * 4 + ty;
        int s = s0 + tx;
        t[cc][tx] = (s < 464) ? bg[((size_t)b * 512 + c0 + cc) * 464 + s] : 0.f;
    }
    __syncthreads();
    const float bv = bias1[z * 512 + c0 + tx];
#pragma unroll
    for (int i = 0; i < 16; ++i) {
        int ss = i * 4 + ty;
        int s = s0 + ss, c = c0 + tx;
        if (s < 472) {
            float v = (s < 464) ? fmaxf(t[tx][ss] + bv, 0.f) : 0.f;
            unsigned short h, l;
            split2(v, h, l);
            size_t o = (size_t)z * 241664 + (size_t)s * 512 + c;
            dh[o] = h; dl[o] = l;
        }
    }
}

// ---------------- hr2o B prestage: pad 7x14 -> [z][160 sp][512 ci] hi/lo ----------------
__global__ __launch_bounds__(256)
void tsplit_pad_k(const float* __restrict__ x, ushort* __restrict__ dh, ushort* __restrict__ dl)
{
    __shared__ float t[64 * 99];
    const int c0 = blockIdx.x * 64, z = blockIdx.y;
    const int tid = threadIdx.x;
#pragma unroll
    for (int i = 0; i < 25; ++i) {
        int idx = tid + i * 256;
        if (idx < 6272) {
            int c = idx / 98, s = idx % 98;
            t[c * 99 + s] = x[((size_t)z * 512 + c0 + c) * 98 + s];
        }
    }
    __syncthreads();
#pragma unroll
    for (int i = 0; i < 40; ++i) {
        int idx = tid + i * 256;   // < 10240 = 160*64
        int sp = idx >> 6, c = idx & 63;
        int r = sp >> 4, col = sp & 15;
        float v = (r >= 1 && r <= 7 && col >= 1 && col <= 14) ? t[c * 99 + (r - 1) * 14 + col - 1] : 0.f;
        unsigned short h, l;
        split2(v, h, l);
        size_t o = (size_t)z * 81920 + (size_t)sp * 512 + c0 + c;
        dh[o] = h; dl[o] = l;
    }
}

// ---------------- temporal mean ----------------
__global__ void tmean_k(const float* __restrict__ f, float* __restrict__ o, int total)
{
    int i = blockIdx.x * blockDim.x + threadIdx.x;
    if (i >= total) return;
    int p = i % HWIN; long bc = i / HWIN;
    const float* src = f + bc * (long)TT * HWIN + p;
    o[i] = (src[0] + src[HWIN] + src[2 * HWIN] + src[3 * HWIN]) * 0.25f;
}

// ---------------- ROI align ----------------
__global__ __launch_bounds__(256)
void roi_align_k(const float* __restrict__ feats, const float* __restrict__ rois,
                 float* __restrict__ roi_feats)
{
    __shared__ int s_o00[196], s_o01[196], s_o10[196], s_o11[196];
    __shared__ float s_w[4][196];
    const int n = blockIdx.x;
    const int b = n / RR;
    const int t = threadIdx.x;
    if (t < 196) {
        float x1 = rois[n * 4 + 0] * WW, y1 = rois[n * 4 + 1] * HH;
        float x2 = rois[n * 4 + 2] * WW, y2 = rois[n * 4 + 3] * HH;
        float rw = fmaxf(x2 - x1, 1.f), rh = fmaxf(y2 - y1, 1.f);
        float bw = rw / 7.f, bh = rh / 7.f;
        int j = t / 14, i = t % 14;
        float gy = (float)(j >> 1) + ((j & 1) + 0.5f) * 0.5f;
        float gx = (float)(i >> 1) + ((i & 1) + 0.5f) * 0.5f;
        float ys = y1 + gy * bh, xs = x1 + gx * bw;
        bool valid = (ys >= -1.f) && (ys <= (float)HH) && (xs >= -1.f) && (xs <= (float)WW);
        float y = fminf(fmaxf(ys, 0.f), (float)(HH - 1));
        float x = fminf(fmaxf(xs, 0.f), (float)(WW - 1));
        float y0f = floorf(y), x0f = floorf(x);
        int iy0 = (int)y0f, ix0 = (int)x0f;
        int iy1 = min(iy0 + 1, HH - 1), ix1 = min(ix0 + 1, WW - 1);
        float ly = y - y0f, lx = x - x0f, hy = 1.f - ly, hx = 1.f - lx;
        float msk = valid ? 1.f : 0.f;
        s_o00[t] = iy0 * WW + ix0; s_o01[t] = iy0 * WW + ix1;
        s_o10[t] = iy1 * WW + ix0; s_o11[t] = iy1 * WW + ix1;
        s_w[0][t] = hy * hx * msk; s_w[1][t] = hy * lx * msk;
        s_w[2][t] = ly * hx * msk; s_w[3][t] = ly * lx * msk;
    }
    __syncthreads();
    for (int c = t; c < REDUCE; c += 256) {
        const float* img = feats + ((long)(b * REDUCE + c)) * HWIN;
        float mx = -INFINITY;
        for (int bin = 0; bin < 49; ++bin) {
            int by_ = bin / 7, bx = bin % 7;
            float s = 0.f;
#pragma unroll
            for (int sy = 0; sy < 2; ++sy)
#pragma unroll
                for (int sx = 0; sx < 2; ++sx) {
                    int ss = (by_ * 2 + sy) * 14 + bx * 2 + sx;
                    s += s_w[0][ss] * img[s_o00[ss]] + s_w[1][ss] * img[s_o01[ss]]
                       + s_w[2][ss] * img[s_o10[ss]] + s_w[3][ss] * img[s_o11[ss]];
                }
            mx = fmaxf(mx, s * 0.25f);
        }
        roi_feats[(long)n * REDUCE + c] = mx;
    }
}

// ---------------- small dense dots ----------------
__global__ void dots_k(const float* __restrict__ Xr, const float* __restrict__ Wt,
                       int ldw, int woff, float* __restrict__ Y,
                       int Nrows, int M, int K, int relu)
{
    int idx = blockIdx.x * blockDim.x + threadIdx.x;
    if (idx >= Nrows * M) return;
    int o = idx / Nrows, n = idx % Nrows;
    const float* xr = Xr + (long)n * K;
    const float* w = Wt + (long)o * ldw + woff;
    float acc = 0.f;
    for (int k = 0; k < K; ++k) acc = fmaf(xr[k], w[k], acc);
    if (relu) acc = fmaxf(acc, 0.f);
    Y[(long)n * M + o] = acc;
}

// ---------------- maxpool 3x3 s2 pad1 ----------------
__global__ void maxpool_k(const float* __restrict__ in, float* __restrict__ out, int total)
{
    int idx = blockIdx.x * blockDim.x + threadIdx.x;
    if (idx >= total) return;
    int ow = idx % PW; int r = idx / PW; int oh = r % PH; long nc = r / PH;
    const float* src = in + nc * NSP2;
    float m = -INFINITY;
    for (int kh = 0; kh < 3; ++kh) {
        int ih = oh * 2 - 1 + kh; if (ih < 0 || ih >= OH2) continue;
        for (int kw = 0; kw < 3; ++kw) {
            int iw = ow * 2 - 1 + kw; if (iw < 0 || iw >= OW2) continue;
            m = fmaxf(m, src[ih * OW2 + iw]);
        }
    }
    out[idx] = m;
}

// ---------------- attention raw scores ----------------
__global__ void att_k(const float* __restrict__ q, const float* __restrict__ k,
                      float* __restrict__ att)
{
    int idx = blockIdx.x * blockDim.x + threadIdx.x;
    const int TOT = BB * 144 * 49;
    if (idx >= TOT) return;
    int ph = idx % 49; int r = idx / 49; int ij = r % 144; int b = r / 144;
    int i = ij / 12, j = ij % 12;
    int p = ph * 2;
    const float* qp = q + ((long)(b * RR + i) * HID) * NSP + p;
    const float* kp = k + ((long)(b * RR + j) * HID) * NSP + p;
    float a0 = 0.f, a1 = 0.f;
#pragma unroll 8
    for (int c = 0; c < HID; ++c) {
        float2 q2 = *(const float2*)(qp + (long)c * NSP);
        float2 k2 = *(const float2*)(kp + (long)c * NSP);
        a0 = fmaf(q2.x, k2.x, a0);
        a1 = fmaf(q2.y, k2.y, a1);
    }
    float* op = att + (((long)(b * 12 + i)) * 12 + j) * NSP + p;
    op[0] = a0 * ATT_SCALE;
    op[1] = a1 * ATT_SCALE;
}

// ---------------- softmax over j ----------------
__global__ void softmax_k(float* __restrict__ att)
{
    int idx = blockIdx.x * blockDim.x + threadIdx.x;
    const int TOT = BB * 12 * NSP;
    if (idx >= TOT) return;
    int p = idx % NSP; int r = idx / NSP; int i = r % 12; int b = r / 12;
    float* base = att + ((long)(b * 12 + i) * 12) * NSP + p;
    float v[12]; float m = -INFINITY;
#pragma unroll
    for (int j = 0; j < 12; ++j) { v[j] = base[j * NSP]; m = fmaxf(m, v[j]); }
    float s = 0.f;
#pragma unroll
    for (int j = 0; j < 12; ++j) { v[j] = expf(v[j] - m); s += v[j]; }
    float inv = 1.f / s;
#pragma unroll
    for (int j = 0; j < 12; ++j) base[j * NSP] = v[j] * inv;
}

// ---------------- virt = att @ v ----------------
__global__ void virt_k(const float* __restrict__ att, const float* __restrict__ v,
                       float* __restrict__ virt)
{
    int idx = blockIdx.x * blockDim.x + threadIdx.x;
    const int TOT = BB * RR * HID * 49;
    if (idx >= TOT) return;
    int ph = idx % 49; int r = idx / 49; int c = r % HID; int r2 = r / HID;
    int i = r2 % RR; int b = r2 / RR;
    int p = 2 * ph;
    const float* ap = att + ((long)(b * 12 + i) * 12) * NSP + p;
    float a0 = 0.f, a1 = 0.f;
#pragma unroll
    for (int j = 0; j < 12; ++j) {
        float w0 = ap[j * NSP], w1 = ap[j * NSP + 1];
        float2 v2 = *(const float2*)(v + (((long)(b * RR + j) * HID) + c) * NSP + p);
        a0 = fmaf(w0, v2.x, a0);
        a1 = fmaf(w1, v2.y, a1);
    }
    float* op = virt + (((long)(b * RR + i) * HID) + c) * NSP + p;
    op[0] = a0; op[1] = a1;
}

// ---------------- per-actor stats ----------------
__global__ __launch_bounds__(256)
void stats_k(const float* __restrict__ virt, float* __restrict__ mu, float* __restrict__ rstd)
{
    int n = blockIdx.x;
    const float* src = virt + (long)n * HID * NSP;
    float s = 0.f, q = 0.f;
    for (int i = threadIdx.x; i < HID * NSP; i += 256) {
        float v = src[i]; s += v; q = fmaf(v, v, q);
    }
    for (int off = 32; off; off >>= 1) { s += __shfl_down(s, off); q += __shfl_down(q, off); }
    __shared__ float ss[4], sq[4];
    int w = threadIdx.x >> 6;
    if ((threadIdx.x & 63) == 0) { ss[w] = s; sq[w] = q; }
    __syncthreads();
    if (threadIdx.x == 0) {
        float S = ss[0] + ss[1] + ss[2] + ss[3];
        float Q = sq[0] + sq[1] + sq[2] + sq[3];
        const float invN = 1.f / (HID * NSP);
        float m = S * invN;
        float var = Q * invN - m * m;
        mu[n] = m; rstd[n] = rsqrtf(var + 1e-5f);
    }
}

// ---------------- normalize + affine + relu ----------------
__global__ void norm_k(float* __restrict__ virt, const float* __restrict__ mu,
                       const float* __restrict__ rstd,
                       const float* __restrict__ gamma, const float* __restrict__ beta)
{
    int idx = blockIdx.x * blockDim.x + threadIdx.x;
    const int TOT = NIMG * HID * NSP;
    if (idx >= TOT) return;
    int n = idx / (HID * NSP);
    int c = (idx / NSP) % HID;
    float val = (virt[idx] - mu[n]) * rstd[n] * gamma[c] + beta[c];
    virt[idx] = fmaxf(val, 0.f);
}

// ---------------- spatial mean ----------------
__global__ void meanpool_k(const float* __restrict__ x, float* __restrict__ high)
{
    int idx = blockIdx.x * blockDim.x + threadIdx.x;
    if (idx >= NIMG * HID) return;
    const float* src = x + (long)idx * NSP;
    float s = 0.f;
    for (int p = 0; p < NSP; ++p) s += src[p];
    high[idx] = s * (1.f / NSP);
}

// ---------------- final FC ----------------
__global__ void final_k(const float* __restrict__ fc1o, const float* __restrict__ high,
                        const float* __restrict__ fc2, float* __restrict__ out)
{
    int idx = blockIdx.x * blockDim.x + threadIdx.x;
    if (idx >= NIMG * NC) return;
    int n = idx / NC, o = idx % NC;
    const float* w = fc2 + (long)o * (2 * HID);
    const float* a = fc1o + (long)n * HID;
    const float* h = high + (long)n * HID;
    float acc = 0.f;
    for (int c = 0; c < HID; ++c) acc = fmaf(a[c], w[c], acc);
    for (int c = 0; c < HID; ++c) acc = fmaf(h[c], w[HID + c], acc);
    out[idx] = acc;
}

// ---------------- launcher ----------------
extern "C" void kernel_launch(void* const* d_in, const int* in_sizes, int n_in,
                              void* d_out, int out_size, void* d_ws, size_t ws_size,
                              hipStream_t stream)
{
    (void)in_sizes; (void)n_in; (void)out_size; (void)ws_size;
    const float* features = (const float*)d_in[0];
    const float* rois     = (const float*)d_in[1];
    const float* w_reduce = (const float*)d_in[2];
    const float* w_conv1  = (const float*)d_in[3];
    const float* w_conv2  = (const float*)d_in[4];
    const float* qw       = (const float*)d_in[5];
    const float* kw       = (const float*)d_in[6];
    const float* vw       = (const float*)d_in[7];
    const float* cw       = (const float*)d_in[8];
    const float* gamma    = (const float*)d_in[9];
    const float* beta     = (const float*)d_in[10];
    const float* fc1      = (const float*)d_in[11];
    const float* fc2      = (const float*)d_in[12];
    float* ws = (float*)d_ws;

    // ---- workspace layout (floats), high-water ~62.0M = 248 MB ----
    float*  tmean = ws + 0;                          // [0, 8552448)  steps 1-2
    ushort* tmTH  = (ushort*)(ws + 8552448);         // tmean^T hi    steps 2-3
    ushort* tmTL  = (ushort*)(ws + 12828672);
    float*  feats = ws + 17104896;                   // 3,801,088     steps 3-5
    ushort* ftTH  = (ushort*)(ws + 0);               // feats^T hi    steps 4-6 (over dead tmean)
    ushort* ftTL  = (ushort*)(ws + 1900544);
    ushort* B2H   = (ushort*)(ws + 0);               // conv2 plane   steps 7-8 (whole R1)
    ushort* B2L   = (ushort*)(ws + 11599872);
    int4*   WTQ   = (int4*)(ws + 0);                 // qkvc weights  hr2o loop (over dead B2)
    float*  bg    = ws + 23199744;                   // 1,900,544     steps 6-7
    float*  out2  = ws + 23199744;                   // 18,579,456    steps 8-9 (over dead bg)
    float*  qb    = ws + 23199744;                   // hr2o loop (over dead out2)
    float*  kb    = ws + 28016640;
    float*  vb    = ws + 32833536;
    ushort* PTH   = (ushort*)(ws + 41779200);        // hr2o B plane hi
    ushort* PTL   = (ushort*)(ws + 45711360);
    float*  xb    = ws + 49643520;                   // 4,816,896
    float*  virt  = ws + 54460416;                   // 4,816,896
    int4*   WTS   = (int4*)(ws + 59277312);          // shared: WT_reduce -> WT_bg -> WTC2
    float*  rf    = ws + 61636608;
    float*  bias1 = ws + 61734912;
    float*  fc1o  = ws + 61784064;
    float*  attb  = ws + 61833216;
    float*  mu    = ws + 61946112;
    float*  rstd  = ws + 61946240;
    float*  high  = ws + 61946368;

    dim3 blk(256);

    // 0. reduce-conv weight prep (plain k): [288][1024][8] hi/lo
    prep_wg_k<<<1152, blk, 0, stream>>>(w_reduce, 2304, 1024, 288, WTS);

    // 1. temporal mean -> tmean [b][2304][464]
    { int tot = BB * WIDTH * HWIN;
      tmean_k<<<(tot + 255) / 256, blk, 0, stream>>>(features, tmean, tot); }

    // 2. transpose+split tmean -> tmeanT [b][464][2304] hi/lo
    tsplit_k<<<dim3(36, 8, 8), blk, 0, stream>>>(tmean, tmTH, tmTL, 2304, 464, 1069056, 1069056);

    // 3. reduce conv (MFMA GEMM): feats[b] = Wr @ tmean[b]
    tap2_k<2, 1, false, false, 2304, 72, 1024, 464L * 2304, 464>
        <<<dim3(5, 8, 8), blk, 0, stream>>>(WTS, nullptr, nullptr, tmTH, tmTL, nullptr,
                                            feats, nullptr, nullptr);

    // 4. transpose+split feats -> featsT [b][464][1024] hi/lo
    tsplit_k<<<dim3(16, 8, 8), blk, 0, stream>>>(feats, ftTH, ftTL, 1024, 464, 475136, 475136);

    // 5. ROI align + actor bias + fc1
    roi_align_k<<<96, blk, 0, stream>>>(feats, rois, rf);
    dots_k<<<(NIMG * HID + 255) / 256, blk, 0, stream>>>(rf, w_conv1, 2048, 1024, bias1, NIMG, HID, REDUCE, 0);
    dots_k<<<(NIMG * HID + 255) / 256, blk, 0, stream>>>(rf, fc1, 1024, 0, fc1o, NIMG, HID, REDUCE, 1);

    // 6. bg GEMM: bg[b] = Wc1_left @ feats[b]  (weight prep overwrites WT_reduce)
    prep_wg_k<<<256, blk, 0, stream>>>(w_conv1, 2048, 512, 128, WTS);
    tap2_k<2, 1, false, false, 1024, 32, 512, 464L * 1024, 464>
        <<<dim3(5, 4, 8), blk, 0, stream>>>(WTS, nullptr, nullptr, ftTH, ftTL, nullptr,
                                            bg, nullptr, nullptr);

    // 7. conv2 weight prep + B prestage (relu(bg+bias))^T
    prep_w_k<<<dim3(1152, 1), blk, 0, stream>>>(w_conv2, w_conv2, w_conv2, w_conv2, WTS);
    tsplit_c2_k<<<dim3(8, 8, 96), blk, 0, stream>>>(bg, bias1, B2H, B2L);

    // 8. conv2 (3x3 valid), relu epilogue -> out2 [96][512][378]
    tap2_k<1, 1, true, false, 512, 144, 512, 472L * 512, 378>
        <<<dim3(4, 4, 96), blk, 0, stream>>>(WTS, nullptr, nullptr, B2H, B2L, nullptr,
                                             out2, nullptr, nullptr);

    // 9. maxpool -> xb (96,512,7,14)
    { int tot = NIMG * HID * NSP;
      maxpool_k<<<(tot + 255) / 256, blk, 0, stream>>>(out2, xb, tot); }

    // 10. HR2O layers
    for (int d = 0; d < DEPTH; ++d) {
        long woff = (long)d * HID * HID * 9;
        prep_w_k<<<dim3(1152, 4), blk, 0, stream>>>(qw + woff, kw + woff, vw + woff, cw + woff, WTQ);

        tsplit_pad_k<<<dim3(8, 96), blk, 0, stream>>>(xb, PTH, PTL);
        tap2_k<0, 3, false, false, 512, 144, 512, 160L * 512, 98>
            <<<dim3(1, 12, 96), blk, 0, stream>>>(WTQ, WTQ + 589824, WTQ + 2 * 589824,
                                                  PTH, PTL, nullptr, qb, kb, vb);

        { int tot = BB * 144 * 49;
          att_k<<<(tot + 255) / 256, blk, 0, stream>>>(qb, kb, attb); }
        { int tot = BB * 12 * NSP;
          softmax_k<<<(tot + 255) / 256, blk, 0, stream>>>(attb); }
        { int tot = BB * RR * HID * 49;
          virt_k<<<(tot + 255) / 256, blk, 0, stream>>>(attb, vb, virt); }
        stats_k<<<96, blk, 0, stream>>>(virt, mu, rstd);
        { int tot = NIMG * HID * NSP;
          norm_k<<<(tot + 255) / 256, blk, 0, stream>>>(virt, mu, rstd, gamma + d * HID, beta + d * HID); }

        tsplit_pad_k<<<dim3(8, 96), blk, 0, stream>>>(virt, PTH, PTL);
        tap2_k<0, 1, false, true, 512, 144, 512, 160L * 512, 98>
            <<<dim3(1, 4, 96), blk, 0, stream>>>(WTQ + 3 * 589824, nullptr, nullptr,
                                                 PTH, PTL, xb, xb, nullptr, nullptr);
    }

    // 11. spatial mean + final FC
    meanpool_k<<<(NIMG * HID + 255) / 256, blk, 0, stream>>>(xb, high);
    final_k<<<(NIMG * NC + 255) / 256, blk, 0, stream>>>(fc1o, high, fc2, (float*)d_out);
}

// Round 4
// 3313.729 us; speedup vs baseline: 3.8700x; 1.0277x over previous
//
#include <hip/hip_runtime.h>
#include <math.h>

// ---------------- problem dims ----------------
#define BB 8
#define RR 12
#define WIDTH 2304
#define TT 4
#define HH 16
#define WW 29
#define HWIN (HH*WW)        // 464
#define REDUCE 1024
#define HID 512
#define NC 60
#define DEPTH 2
#define NIMG (BB*RR)        // 96
#define OH2 14
#define OW2 27
#define NSP2 (OH2*OW2)      // 378
#define PH 7
#define PW 14
#define NSP (PH*PW)         // 98
#define ATT_SCALE 0.044194173824159216f

typedef __attribute__((ext_vector_type(8))) short short8;
typedef __attribute__((ext_vector_type(4))) float floatx4;

// ---------------- helpers ----------------
__device__ __forceinline__ void split2(float v, unsigned short& h, unsigned short& l)
{
    union { float f; unsigned u; } c; c.f = v;
    unsigned hb = c.u & 0xffff0000u;
    h = (unsigned short)(hb >> 16);
    union { float f; unsigned u; } hc; hc.u = hb;
    float r = v - hc.f;
    union { float f; unsigned u; } rc; rc.f = r;
    unsigned ru = rc.u + 0x7fffu + ((rc.u >> 16) & 1u);
    l = (unsigned short)(ru >> 16);
}

__device__ __forceinline__ void gll16(const void* g, void* l)
{
    __builtin_amdgcn_global_load_lds((const __attribute__((address_space(1))) void*)g,
                                     (__attribute__((address_space(3))) void*)l,
                                     16, 0, 0);
}

#define MFMA3(d, ah_, al_, bh_, bl_) \
    d = __builtin_amdgcn_mfma_f32_16x16x32_bf16(ah_, bh_, d, 0, 0, 0); \
    d = __builtin_amdgcn_mfma_f32_16x16x32_bf16(ah_, bl_, d, 0, 0, 0); \
    d = __builtin_amdgcn_mfma_f32_16x16x32_bf16(al_, bh_, d, 0, 0, 0);

// ---------------- 2-phase pipelined split-bf16 MFMA implicit-GEMM ----------------
// Weights pre-tiled [K/8][MTOT][8] bf16 (hi plane, then lo plane at +KSTN*4*MTOT int4).
// B prestaged as transposed bf16 hi/lo planes [sp][KW] per z.
// TYPE 0: hr2o pad-1 3x3 conv; TYPE 1: conv2 valid 3x3; TYPE 2: plain GEMM.
// ZX: z = blockIdx.x (weight-reuse-friendly order for many-z conv dispatches).
template<int TYPE, int NSEL, bool RELU, bool RESID, int KW, int KSTN, int MTOT, long PLSTR, int NREAL, bool ZX>
__global__ __launch_bounds__(256, 2)
void tap2_k(const int4* __restrict__ WA0, const int4* __restrict__ WA1, const int4* __restrict__ WA2,
            const ushort* __restrict__ BH, const ushort* __restrict__ BL,
            const float* __restrict__ Res,
            float* __restrict__ Y0, float* __restrict__ Y1, float* __restrict__ Y2)
{
    __shared__ int4 L[3872];
    const int tid = threadIdx.x;
    const int z  = ZX ? blockIdx.x : blockIdx.z;
    const int nb = ZX ? blockIdx.z : blockIdx.x;
    int by = blockIdx.y;

    const int4* WA = WA0; float* Y = Y0;
    if (NSEL == 3) {
        int sel = by >> 2; by &= 3;
        if (sel == 1) { WA = WA1; Y = Y1; }
        else if (sel == 2) { WA = WA2; Y = Y2; }
    }
    const int m0 = by * 128;
    const int lane = tid & 63, wv = tid >> 6;
    const int lrow = lane >> 4, lcol = lane & 15;
    constexpr long ALO = (long)KSTN * 4 * MTOT;

    // B-unit per-thread constants: u = g*112 + n
    int nU[2], gU[2]; long pbU[2]; bool vU[2];
#pragma unroll
    for (int it = 0; it < 2; ++it) {
        int u = tid + (it << 8);
        vU[it] = (u < 448);
        int uu = vU[it] ? u : 0;
        nU[it] = uu % 112; gU[it] = uu / 112;
        if (TYPE == 0) pbU[it] = nU[it];
        else {
            int gn = nb * 112 + nU[it];
            if (TYPE == 1) pbU[it] = (gn >> 5) * 29 + (gn & 31);
            else pbU[it] = min(gn, NREAL - 1);
        }
    }
    const ushort* BHz = BH + (size_t)z * PLSTR;
    const ushort* BLz = BL + (size_t)z * PLSTR;

    floatx4 acc[2][7];
#pragma unroll
    for (int mf = 0; mf < 2; ++mf)
#pragma unroll
        for (int nf = 0; nf < 7; ++nf) acc[mf][nf] = (floatx4){0.f, 0.f, 0.f, 0.f};

    short8 rbh[2], rbl[2];

#define STAGE_ISSUE(KST, BUF) { \
    int k8 = (KST) * 4; \
    _Pragma("unroll") \
    for (int j = 0; j < 4; ++j) { \
        int h = wv * 4 + j, p = h >> 3, g = (h >> 1) & 3, hf = h & 1; \
        gll16(WA + (p ? ALO : 0) + (long)(k8 + g) * MTOT + m0 + hf * 64 + lane, \
              L + (BUF) * 1936 + (p * 4 + g) * 129 + hf * 64); \
    } \
    int tap, ci0, shv; \
    if (TYPE == 2) { tap = 0; ci0 = (KST) << 5; shv = 0; } \
    else { tap = (KST) >> 4; ci0 = ((KST) & 15) << 5; int t3 = tap / 3; \
           shv = (TYPE == 0) ? t3 * 16 + (tap - t3 * 3) : t3 * 29 + (tap - t3 * 3); } \
    _Pragma("unroll") \
    for (int it = 0; it < 2; ++it) if (vU[it]) { \
        size_t o = (size_t)(pbU[it] + shv) * KW + ci0 + gU[it] * 8; \
        rbh[it] = *(const short8*)(BHz + o); \
        rbl[it] = *(const short8*)(BLz + o); \
    } }

#define STAGE_WRITE(BUF) { \
    _Pragma("unroll") \
    for (int it = 0; it < 2; ++it) if (vU[it]) { \
        *((short8*)(L + (BUF) * 1936 + 1032 + gU[it] * 113 + nU[it])) = rbh[it]; \
        *((short8*)(L + (BUF) * 1936 + 1484 + gU[it] * 113 + nU[it])) = rbl[it]; \
    } }

#define COMPUTE(BUF) { \
    const int4* Lc = L + (BUF) * 1936; \
    short8 ah[2], al[2]; \
    _Pragma("unroll") \
    for (int mf = 0; mf < 2; ++mf) { \
        int au = lrow * 129 + (wv * 2 + mf) * 16 + lcol; \
        ah[mf] = *(const short8*)(Lc + au); \
        al[mf] = *(const short8*)(Lc + 516 + au); \
    } \
    _Pragma("unroll") \
    for (int nf = 0; nf < 7; ++nf) { \
        int bu = 1032 + lrow * 113 + nf * 16 + lcol; \
        short8 bh = *(const short8*)(Lc + bu); \
        short8 bl = *(const short8*)(Lc + bu + 452); \
        _Pragma("unroll") \
        for (int mf = 0; mf < 2; ++mf) { MFMA3(acc[mf][nf], ah[mf], al[mf], bh, bl) } \
    } }

    // prologue
    STAGE_ISSUE(0, 0)
    STAGE_WRITE(0)
    __syncthreads();

    int cur = 0;
    for (int kst = 0; kst < KSTN; ++kst) {
        int nxt = cur ^ 1;
        bool more = (kst + 1 < KSTN);
        if (more) STAGE_ISSUE(kst + 1, nxt)
        COMPUTE(cur)
        if (more) { STAGE_WRITE(nxt) __syncthreads(); }
        cur = nxt;
    }

    // epilogue
#pragma unroll
    for (int mf = 0; mf < 2; ++mf) {
        int m = m0 + wv * 32 + mf * 16 + lrow * 4;
#pragma unroll
        for (int nf = 0; nf < 7; ++nf) {
            int col = nf * 16 + lcol;
            int sp, realn; bool ok;
            if (TYPE == 0) { int oh = col >> 4, ow = col & 15; ok = ow < 14; sp = oh * 14 + ow; realn = 98; }
            else if (TYPE == 1) { int gn = nb * 112 + col; int oh = gn >> 5, ow = gn & 31; ok = ow < 27; sp = oh * 27 + ow; realn = 378; }
            else { int gn = nb * 112 + col; ok = gn < NREAL; sp = gn; realn = NREAL; }
            if (ok) {
#pragma unroll
                for (int r = 0; r < 4; ++r) {
                    size_t idx = ((size_t)z * MTOT + m + r) * realn + sp;
                    float v = acc[mf][nf][r];
                    if (RESID) v += Res[idx];
                    if (RELU) v = fmaxf(v, 0.f);
                    Y[idx] = v;
                }
            }
        }
    }
#undef STAGE_ISSUE
#undef STAGE_WRITE
#undef COMPUTE
}

// ---------------- weight prep: tap-reordered 3x3 convs [512][4608] -> [576][512][8] hi/lo ----------------
__global__ void prep_w_k(const float* __restrict__ s0, const float* __restrict__ s1,
                         const float* __restrict__ s2, const float* __restrict__ s3,
                         int4* __restrict__ dst)
{
    const int c = blockIdx.y;
    const float* src = (c == 0) ? s0 : (c == 1) ? s1 : (c == 2) ? s2 : s3;
    int4* dh = dst + (size_t)c * 589824;
    int4* dl = dh + 294912;
    int idx = blockIdx.x * 256 + threadIdx.x;
    if (idx >= 294912) return;
    int g8 = idx / 512, m = idx & 511;
    unsigned hw[4], lw[4];
#pragma unroll
    for (int j = 0; j < 4; ++j) {
        int k1 = g8 * 8 + 2 * j, k2 = k1 + 1;
        float v1 = src[(size_t)m * 4608 + ((k1 & 511) * 9 + (k1 >> 9))];
        float v2 = src[(size_t)m * 4608 + ((k2 & 511) * 9 + (k2 >> 9))];
        unsigned short h0, l0, h1, l1;
        split2(v1, h0, l0); split2(v2, h1, l1);
        hw[j] = (unsigned)h0 | ((unsigned)h1 << 16);
        lw[j] = (unsigned)l0 | ((unsigned)l1 << 16);
    }
    dh[idx] = make_int4(hw[0], hw[1], hw[2], hw[3]);
    dl[idx] = make_int4(lw[0], lw[1], lw[2], lw[3]);
}

// ---------------- weight prep: plain GEMM A [M][ldw] -> [K/8][M][8] hi/lo ----------------
__global__ void prep_wg_k(const float* __restrict__ src, int ldw, int M, int K8,
                          int4* __restrict__ dst)
{
    int idx = blockIdx.x * 256 + threadIdx.x;
    if (idx >= K8 * M) return;
    int g8 = idx / M, m = idx % M;
    unsigned hw[4], lw[4];
#pragma unroll
    for (int j = 0; j < 4; ++j) {
        int k1 = g8 * 8 + 2 * j;
        float v1 = src[(size_t)m * ldw + k1];
        float v2 = src[(size_t)m * ldw + k1 + 1];
        unsigned short h0, l0, h1, l1;
        split2(v1, h0, l0); split2(v2, h1, l1);
        hw[j] = (unsigned)h0 | ((unsigned)h1 << 16);
        lw[j] = (unsigned)l0 | ((unsigned)l1 << 16);
    }
    dst[idx] = make_int4(hw[0], hw[1], hw[2], hw[3]);
    dst[(size_t)K8 * M + idx] = make_int4(lw[0], lw[1], lw[2], lw[3]);
}

// ---------------- transpose + split: src [C][S] fp32 -> dst [S][C] bf16 hi/lo ----------------
__global__ __launch_bounds__(256)
void tsplit_k(const float* __restrict__ src, ushort* __restrict__ dh, ushort* __restrict__ dl,
              int C, int S, long zsrc, long zdst)
{
    __shared__ float t[64][65];
    const int c0 = blockIdx.x * 64, s0 = blockIdx.y * 64, z = blockIdx.z;
    const float* sz = src + (size_t)z * zsrc;
    const int tx = threadIdx.x & 63, ty = threadIdx.x >> 6;
#pragma unroll
    for (int i = 0; i < 16; ++i) {
        int cc = i * 4 + ty;
        int c = c0 + cc, s = s0 + tx;
        t[cc][tx] = (c < C && s < S) ? sz[(size_t)c * S + s] : 0.f;
    }
    __syncthreads();
#pragma unroll
    for (int i = 0; i < 16; ++i) {
        int ss = i * 4 + ty;
        int s = s0 + ss, c = c0 + tx;
        if (s < S && c < C) {
            unsigned short h, l;
            split2(t[tx][ss], h, l);
            size_t o = (size_t)z * zdst + (size_t)s * C + c;
            dh[o] = h; dl[o] = l;
        }
    }
}

// ---------------- conv2 B prestage: relu(bg[b] + bias1[z])^T -> [z][472][512] hi/lo ----------------
__global__ __launch_bounds__(256)
void tsplit_c2_k(const float* __restrict__ bg, const float* __restrict__ bias1,
                 ushort* __restrict__ dh, ushort* __restrict__ dl)
{
    __shared__ float t[64][65];
    const int c0 = blockIdx.x * 64, s0 = blockIdx.y * 64, z = blockIdx.z;
    const int b = z / RR;
    const int tx = threadIdx.x & 63, ty = threadIdx.x >> 6;
#pragma unroll
    for (int i = 0; i < 16; ++i) {
        int cc = i * 4 + ty;
        int s = s0 + tx;
        t[cc][tx] = (s < 464) ? bg[((size_t)b * 512 + c0 + cc) * 464 + s] : 0.f;
    }
    __syncthreads();
    const float bv = bias1[z * 512 + c0 + tx];
#pragma unroll
    for (int i = 0; i < 16; ++i) {
        int ss = i * 4 + ty;
        int s = s0 + ss, c = c0 + tx;
        if (s < 472) {
            float v = (s < 464) ? fmaxf(t[tx][ss] + bv, 0.f) : 0.f;
            unsigned short h, l;
            split2(v, h, l);
            size_t o = (size_t)z * 241664 + (size_t)s * 512 + c;
            dh[o] = h; dl[o] = l;
        }
    }
}

// ---------------- hr2o B prestage: pad 7x14 -> [z][160 sp][512 ci] hi/lo ----------------
__global__ __launch_bounds__(256)
void tsplit_pad_k(const float* __restrict__ x, ushort* __restrict__ dh, ushort* __restrict__ dl)
{
    __shared__ float t[64 * 99];
    const int c0 = blockIdx.x * 64, z = blockIdx.y;
    const int tid = threadIdx.x;
#pragma unroll
    for (int i = 0; i < 25; ++i) {
        int idx = tid + i * 256;
        if (idx < 6272) {
            int c = idx / 98, s = idx % 98;
            t[c * 99 + s] = x[((size_t)z * 512 + c0 + c) * 98 + s];
        }
    }
    __syncthreads();
#pragma unroll
    for (int i = 0; i < 40; ++i) {
        int idx = tid + i * 256;   // < 10240 = 160*64
        int sp = idx >> 6, c = idx & 63;
        int r = sp >> 4, col = sp & 15;
        float v = (r >= 1 && r <= 7 && col >= 1 && col <= 14) ? t[c * 99 + (r - 1) * 14 + col - 1] : 0.f;
        unsigned short h, l;
        split2(v, h, l);
        size_t o = (size_t)z * 81920 + (size_t)sp * 512 + c0 + c;
        dh[o] = h; dl[o] = l;
    }
}

// ---------------- temporal mean ----------------
__global__ void tmean_k(const float* __restrict__ f, float* __restrict__ o, int total)
{
    int i = blockIdx.x * blockDim.x + threadIdx.x;
    if (i >= total) return;
    int p = i % HWIN; long bc = i / HWIN;
    const float* src = f + bc * (long)TT * HWIN + p;
    o[i] = (src[0] + src[HWIN] + src[2 * HWIN] + src[3 * HWIN]) * 0.25f;
}

// ---------------- ROI align ----------------
__global__ __launch_bounds__(256)
void roi_align_k(const float* __restrict__ feats, const float* __restrict__ rois,
                 float* __restrict__ roi_feats)
{
    __shared__ int s_o00[196], s_o01[196], s_o10[196], s_o11[196];
    __shared__ float s_w[4][196];
    const int n = blockIdx.x;
    const int b = n / RR;
    const int t = threadIdx.x;
    if (t < 196) {
        float x1 = rois[n * 4 + 0] * WW, y1 = rois[n * 4 + 1] * HH;
        float x2 = rois[n * 4 + 2] * WW, y2 = rois[n * 4 + 3] * HH;
        float rw = fmaxf(x2 - x1, 1.f), rh = fmaxf(y2 - y1, 1.f);
        float bw = rw / 7.f, bh = rh / 7.f;
        int j = t / 14, i = t % 14;
        float gy = (float)(j >> 1) + ((j & 1) + 0.5f) * 0.5f;
        float gx = (float)(i >> 1) + ((i & 1) + 0.5f) * 0.5f;
        float ys = y1 + gy * bh, xs = x1 + gx * bw;
        bool valid = (ys >= -1.f) && (ys <= (float)HH) && (xs >= -1.f) && (xs <= (float)WW);
        float y = fminf(fmaxf(ys, 0.f), (float)(HH - 1));
        float x = fminf(fmaxf(xs, 0.f), (float)(WW - 1));
        float y0f = floorf(y), x0f = floorf(x);
        int iy0 = (int)y0f, ix0 = (int)x0f;
        int iy1 = min(iy0 + 1, HH - 1), ix1 = min(ix0 + 1, WW - 1);
        float ly = y - y0f, lx = x - x0f, hy = 1.f - ly, hx = 1.f - lx;
        float msk = valid ? 1.f : 0.f;
        s_o00[t] = iy0 * WW + ix0; s_o01[t] = iy0 * WW + ix1;
        s_o10[t] = iy1 * WW + ix0; s_o11[t] = iy1 * WW + ix1;
        s_w[0][t] = hy * hx * msk; s_w[1][t] = hy * lx * msk;
        s_w[2][t] = ly * hx * msk; s_w[3][t] = ly * lx * msk;
    }
    __syncthreads();
    for (int c = t; c < REDUCE; c += 256) {
        const float* img = feats + ((long)(b * REDUCE + c)) * HWIN;
        float mx = -INFINITY;
        for (int bin = 0; bin < 49; ++bin) {
            int by_ = bin / 7, bx = bin % 7;
            float s = 0.f;
#pragma unroll
            for (int sy = 0; sy < 2; ++sy)
#pragma unroll
                for (int sx = 0; sx < 2; ++sx) {
                    int ss = (by_ * 2 + sy) * 14 + bx * 2 + sx;
                    s += s_w[0][ss] * img[s_o00[ss]] + s_w[1][ss] * img[s_o01[ss]]
                       + s_w[2][ss] * img[s_o10[ss]] + s_w[3][ss] * img[s_o11[ss]];
                }
            mx = fmaxf(mx, s * 0.25f);
        }
        roi_feats[(long)n * REDUCE + c] = mx;
    }
}

// ---------------- small dense dots ----------------
__global__ void dots_k(const float* __restrict__ Xr, const float* __restrict__ Wt,
                       int ldw, int woff, float* __restrict__ Y,
                       int Nrows, int M, int K, int relu)
{
    int idx = blockIdx.x * blockDim.x + threadIdx.x;
    if (idx >= Nrows * M) return;
    int o = idx / Nrows, n = idx % Nrows;
    const float* xr = Xr + (long)n * K;
    const float* w = Wt + (long)o * ldw + woff;
    float acc = 0.f;
    for (int k = 0; k < K; ++k) acc = fmaf(xr[k], w[k], acc);
    if (relu) acc = fmaxf(acc, 0.f);
    Y[(long)n * M + o] = acc;
}

// ---------------- maxpool 3x3 s2 pad1 ----------------
__global__ void maxpool_k(const float* __restrict__ in, float* __restrict__ out, int total)
{
    int idx = blockIdx.x * blockDim.x + threadIdx.x;
    if (idx >= total) return;
    int ow = idx % PW; int r = idx / PW; int oh = r % PH; long nc = r / PH;
    const float* src = in + nc * NSP2;
    float m = -INFINITY;
    for (int kh = 0; kh < 3; ++kh) {
        int ih = oh * 2 - 1 + kh; if (ih < 0 || ih >= OH2) continue;
        for (int kw = 0; kw < 3; ++kw) {
            int iw = ow * 2 - 1 + kw; if (iw < 0 || iw >= OW2) continue;
            m = fmaxf(m, src[ih * OW2 + iw]);
        }
    }
    out[idx] = m;
}

// ---------------- fused attention scores + softmax ----------------
// grid (8 b, 14 pg); pg covers 7 p's. LDS-staged q/k c-chunks; softmax over j in-block.
__global__ __launch_bounds__(256)
void att2_k(const float* __restrict__ q, const float* __restrict__ k, float* __restrict__ att)
{
    __shared__ float qs[5376];   // [12][64][7]
    __shared__ float ks[5376];
    __shared__ float sc[1008];   // [144][7]
    const int b = blockIdx.x, p0 = blockIdx.y * 7;
    const int tid = threadIdx.x;

    int itI[4], itJ[4], itP[4]; bool itV[4];
#pragma unroll
    for (int r = 0; r < 4; ++r) {
        int item = tid + (r << 8);
        itV[r] = item < 1008;
        int it = itV[r] ? item : 0;
        int ij = it / 7; itP[r] = it % 7;
        itI[r] = ij / 12; itJ[r] = ij % 12;
    }
    float acc[4] = {0.f, 0.f, 0.f, 0.f};

    for (int cc0 = 0; cc0 < 512; cc0 += 64) {
        for (int l = tid; l < 5376; l += 256) {
            int i = l / 448, r = l % 448, c = r / 7, p = r % 7;
            size_t off = ((size_t)(b * 12 + i) * 512 + cc0 + c) * 98 + p0 + p;
            qs[l] = q[off];
            ks[l] = k[off];
        }
        __syncthreads();
#pragma unroll
        for (int r = 0; r < 4; ++r) {
            if (itV[r]) {
                const float* qp = qs + itI[r] * 448 + itP[r];
                const float* kp = ks + itJ[r] * 448 + itP[r];
                float a = acc[r];
#pragma unroll 8
                for (int c = 0; c < 64; ++c) a = fmaf(qp[c * 7], kp[c * 7], a);
                acc[r] = a;
            }
        }
        __syncthreads();
    }
#pragma unroll
    for (int r = 0; r < 4; ++r)
        if (itV[r]) sc[tid + (r << 8)] = acc[r] * ATT_SCALE;
    __syncthreads();
    if (tid < 84) {
        int i = tid / 7, p = tid % 7;
        float m = -INFINITY;
        float v[12];
#pragma unroll
        for (int j = 0; j < 12; ++j) { v[j] = sc[(i * 12 + j) * 7 + p]; m = fmaxf(m, v[j]); }
        float s = 0.f;
#pragma unroll
        for (int j = 0; j < 12; ++j) { v[j] = expf(v[j] - m); s += v[j]; }
        float inv = 1.f / s;
#pragma unroll
        for (int j = 0; j < 12; ++j)
            att[((size_t)(b * 12 + i) * 12 + j) * 98 + p0 + p] = v[j] * inv;
    }
}

// ---------------- virt = att @ v : one thread computes all 12 i per (c,p) ----------------
// grid (8 b, 8 cb); att[b] staged in LDS once; v read exactly once.
__global__ __launch_bounds__(256)
void virt2_k(const float* __restrict__ att, const float* __restrict__ v, float* __restrict__ virt)
{
    __shared__ float as_[14112];   // [12][12][98]
    const int b = blockIdx.x, cb = blockIdx.y;
    const int tid = threadIdx.x;
    for (int l = tid; l < 14112; l += 256) as_[l] = att[(size_t)b * 14112 + l];
    __syncthreads();

    for (int it = tid; it < 6272; it += 256) {
        int c = cb * 64 + it / 98, p = it % 98;
        float o[12];
#pragma unroll
        for (int i = 0; i < 12; ++i) o[i] = 0.f;
#pragma unroll
        for (int j = 0; j < 12; ++j) {
            float vj = v[((size_t)(b * 12 + j) * 512 + c) * 98 + p];
#pragma unroll
            for (int i = 0; i < 12; ++i) o[i] = fmaf(as_[(i * 12 + j) * 98 + p], vj, o[i]);
        }
#pragma unroll
        for (int i = 0; i < 12; ++i)
            virt[((size_t)(b * 12 + i) * 512 + c) * 98 + p] = o[i];
    }
}

// ---------------- per-actor stats ----------------
__global__ __launch_bounds__(256)
void stats_k(const float* __restrict__ virt, float* __restrict__ mu, float* __restrict__ rstd)
{
    int n = blockIdx.x;
    const float* src = virt + (long)n * HID * NSP;
    float s = 0.f, q = 0.f;
    for (int i = threadIdx.x; i < HID * NSP; i += 256) {
        float v = src[i]; s += v; q = fmaf(v, v, q);
    }
    for (int off = 32; off; off >>= 1) { s += __shfl_down(s, off); q += __shfl_down(q, off); }
    __shared__ float ss[4], sq[4];
    int w = threadIdx.x >> 6;
    if ((threadIdx.x & 63) == 0) { ss[w] = s; sq[w] = q; }
    __syncthreads();
    if (threadIdx.x == 0) {
        float S = ss[0] + ss[1] + ss[2] + ss[3];
        float Q = sq[0] + sq[1] + sq[2] + sq[3];
        const float invN = 1.f / (HID * NSP);
        float m = S * invN;
        float var = Q * invN - m * m;
        mu[n] = m; rstd[n] = rsqrtf(var + 1e-5f);
    }
}

// ---------------- normalize + affine + relu ----------------
__global__ void norm_k(float* __restrict__ virt, const float* __restrict__ mu,
                       const float* __restrict__ rstd,
                       const float* __restrict__ gamma, const float* __restrict__ beta)
{
    int idx = blockIdx.x * blockDim.x + threadIdx.x;
    const int TOT = NIMG * HID * NSP;
    if (idx >= TOT) return;
    int n = idx / (HID * NSP);
    int c = (idx / NSP) % HID;
    float val = (virt[idx] - mu[n]) * rstd[n] * gamma[c] + beta[c];
    virt[idx] = fmaxf(val, 0.f);
}

// ---------------- spatial mean ----------------
__global__ void meanpool_k(const float* __restrict__ x, float* __restrict__ high)
{
    int idx = blockIdx.x * blockDim.x + threadIdx.x;
    if (idx >= NIMG * HID) return;
    const float* src = x + (long)idx * NSP;
    float s = 0.f;
    for (int p = 0; p < NSP; ++p) s += src[p];
    high[idx] = s * (1.f / NSP);
}

// ---------------- final FC ----------------
__global__ void final_k(const float* __restrict__ fc1o, const float* __restrict__ high,
                        const float* __restrict__ fc2, float* __restrict__ out)
{
    int idx = blockIdx.x * blockDim.x + threadIdx.x;
    if (idx >= NIMG * NC) return;
    int n = idx / NC, o = idx % NC;
    const float* w = fc2 + (long)o * (2 * HID);
    const float* a = fc1o + (long)n * HID;
    const float* h = high + (long)n * HID;
    float acc = 0.f;
    for (int c = 0; c < HID; ++c) acc = fmaf(a[c], w[c], acc);
    for (int c = 0; c < HID; ++c) acc = fmaf(h[c], w[HID + c], acc);
    out[idx] = acc;
}

// ---------------- launcher ----------------
extern "C" void kernel_launch(void* const* d_in, const int* in_sizes, int n_in,
                              void* d_out, int out_size, void* d_ws, size_t ws_size,
                              hipStream_t stream)
{
    (void)in_sizes; (void)n_in; (void)out_size; (void)ws_size;
    const float* features = (const float*)d_in[0];
    const float* rois     = (const float*)d_in[1];
    const float* w_reduce = (const float*)d_in[2];
    const float* w_conv1  = (const float*)d_in[3];
    const float* w_conv2  = (const float*)d_in[4];
    const float* qw       = (const float*)d_in[5];
    const float* kw       = (const float*)d_in[6];
    const float* vw       = (const float*)d_in[7];
    const float* cw       = (const float*)d_in[8];
    const float* gamma    = (const float*)d_in[9];
    const float* beta     = (const float*)d_in[10];
    const float* fc1      = (const float*)d_in[11];
    const float* fc2      = (const float*)d_in[12];
    float* ws = (float*)d_ws;

    // ---- workspace layout (floats), high-water ~62.0M = 248 MB ----
    float*  tmean = ws + 0;                          // [0, 8552448)  steps 1-2
    ushort* tmTH  = (ushort*)(ws + 8552448);         // tmean^T hi    steps 2-3
    ushort* tmTL  = (ushort*)(ws + 12828672);
    float*  feats = ws + 17104896;                   // 3,801,088     steps 3-5
    ushort* ftTH  = (ushort*)(ws + 0);               // feats^T hi    steps 4-6 (over dead tmean)
    ushort* ftTL  = (ushort*)(ws + 1900544);
    ushort* B2H   = (ushort*)(ws + 0);               // conv2 plane   steps 7-8
    ushort* B2L   = (ushort*)(ws + 11599872);
    int4*   WTQ   = (int4*)(ws + 0);                 // qkvc weights  hr2o loop (over dead B2)
    float*  bg    = ws + 23199744;                   // 1,900,544     steps 6-7
    float*  out2  = ws + 23199744;                   // 18,579,456    steps 8-9 (over dead bg)
    float*  qb    = ws + 23199744;                   // hr2o loop (over dead out2)
    float*  kb    = ws + 28016640;
    float*  vb    = ws + 32833536;
    ushort* PTH   = (ushort*)(ws + 41779200);        // hr2o B plane hi
    ushort* PTL   = (ushort*)(ws + 45711360);
    float*  xb    = ws + 49643520;                   // 4,816,896
    float*  virt  = ws + 54460416;                   // 4,816,896
    int4*   WTS   = (int4*)(ws + 59277312);          // shared: WT_reduce -> WT_bg -> WTC2
    float*  rf    = ws + 61636608;
    float*  bias1 = ws + 61734912;
    float*  fc1o  = ws + 61784064;
    float*  attb  = ws + 61833216;
    float*  mu    = ws + 61946112;
    float*  rstd  = ws + 61946240;
    float*  high  = ws + 61946368;

    dim3 blk(256);

    // 0. reduce-conv weight prep (plain k): [288][1024][8] hi/lo
    prep_wg_k<<<1152, blk, 0, stream>>>(w_reduce, 2304, 1024, 288, WTS);

    // 1. temporal mean -> tmean [b][2304][464]
    { int tot = BB * WIDTH * HWIN;
      tmean_k<<<(tot + 255) / 256, blk, 0, stream>>>(features, tmean, tot); }

    // 2. transpose+split tmean -> tmeanT [b][464][2304] hi/lo
    tsplit_k<<<dim3(36, 8, 8), blk, 0, stream>>>(tmean, tmTH, tmTL, 2304, 464, 1069056, 1069056);

    // 3. reduce conv (MFMA GEMM): feats[b] = Wr @ tmean[b]   (z=8 small: keep z-slow order)
    tap2_k<2, 1, false, false, 2304, 72, 1024, 464L * 2304, 464, false>
        <<<dim3(5, 8, 8), blk, 0, stream>>>(WTS, nullptr, nullptr, tmTH, tmTL, nullptr,
                                            feats, nullptr, nullptr);

    // 4. transpose+split feats -> featsT [b][464][1024] hi/lo
    tsplit_k<<<dim3(16, 8, 8), blk, 0, stream>>>(feats, ftTH, ftTL, 1024, 464, 475136, 475136);

    // 5. ROI align + actor bias + fc1
    roi_align_k<<<96, blk, 0, stream>>>(feats, rois, rf);
    dots_k<<<(NIMG * HID + 255) / 256, blk, 0, stream>>>(rf, w_conv1, 2048, 1024, bias1, NIMG, HID, REDUCE, 0);
    dots_k<<<(NIMG * HID + 255) / 256, blk, 0, stream>>>(rf, fc1, 1024, 0, fc1o, NIMG, HID, REDUCE, 1);

    // 6. bg GEMM: bg[b] = Wc1_left @ feats[b]
    prep_wg_k<<<256, blk, 0, stream>>>(w_conv1, 2048, 512, 128, WTS);
    tap2_k<2, 1, false, false, 1024, 32, 512, 464L * 1024, 464, false>
        <<<dim3(5, 4, 8), blk, 0, stream>>>(WTS, nullptr, nullptr, ftTH, ftTL, nullptr,
                                            bg, nullptr, nullptr);

    // 7. conv2 weight prep + B prestage (relu(bg+bias))^T
    prep_w_k<<<dim3(1152, 1), blk, 0, stream>>>(w_conv2, w_conv2, w_conv2, w_conv2, WTS);
    tsplit_c2_k<<<dim3(8, 8, 96), blk, 0, stream>>>(bg, bias1, B2H, B2L);

    // 8. conv2 (3x3 valid), relu epilogue -> out2 [96][512][378]   z-fast order
    tap2_k<1, 1, true, false, 512, 144, 512, 472L * 512, 378, true>
        <<<dim3(96, 4, 4), blk, 0, stream>>>(WTS, nullptr, nullptr, B2H, B2L, nullptr,
                                             out2, nullptr, nullptr);

    // 9. maxpool -> xb (96,512,7,14)
    { int tot = NIMG * HID * NSP;
      maxpool_k<<<(tot + 255) / 256, blk, 0, stream>>>(out2, xb, tot); }

    // 10. HR2O layers
    for (int d = 0; d < DEPTH; ++d) {
        long woff = (long)d * HID * HID * 9;
        prep_w_k<<<dim3(1152, 4), blk, 0, stream>>>(qw + woff, kw + woff, vw + woff, cw + woff, WTQ);

        tsplit_pad_k<<<dim3(8, 96), blk, 0, stream>>>(xb, PTH, PTL);
        tap2_k<0, 3, false, false, 512, 144, 512, 160L * 512, 98, true>
            <<<dim3(96, 12, 1), blk, 0, stream>>>(WTQ, WTQ + 589824, WTQ + 2 * 589824,
                                                  PTH, PTL, nullptr, qb, kb, vb);

        att2_k<<<dim3(8, 14), blk, 0, stream>>>(qb, kb, attb);
        virt2_k<<<dim3(8, 8), blk, 0, stream>>>(attb, vb, virt);
        stats_k<<<96, blk, 0, stream>>>(virt, mu, rstd);
        { int tot = NIMG * HID * NSP;
          norm_k<<<(tot + 255) / 256, blk, 0, stream>>>(virt, mu, rstd, gamma + d * HID, beta + d * HID); }

        tsplit_pad_k<<<dim3(8, 96), blk, 0, stream>>>(virt, PTH, PTL);
        tap2_k<0, 1, false, true, 512, 144, 512, 160L * 512, 98, true>
            <<<dim3(96, 4, 1), blk, 0, stream>>>(WTQ + 3 * 589824, nullptr, nullptr,
                                                 PTH, PTL, xb, xb, nullptr, nullptr);
    }

    // 11. spatial mean + final FC
    meanpool_k<<<(NIMG * HID + 255) / 256, blk, 0, stream>>>(xb, high);
    final_k<<<(NIMG * NC + 255) / 256, blk, 0, stream>>>(fc1o, high, fc2, (float*)d_out);
}